// Round 13
// baseline (197.400 us; speedup 1.0000x reference)
//
#include <hip/hip_runtime.h>

// Attention_29583734734990 : resid[4,2048,1024] f32, w_q/k/v[16,1024,64], w_o[16,64,1024]
// out[4,2048,1024] f32.  bf16 MFMA pipeline (threshold is bf16-floor 3.14e-2).
//
// GEMM input arrays (Xb, W3, Wo, Zb) are stored SLOT-SWIZZLED: within each
// 32-element k-chunk, 16B slot index ^= ((row>>1)&3).  global_load_lds stages
// chunks linearly; LDS readers XOR the same involution (rule-21 both-sides).

typedef __attribute__((ext_vector_type(8))) short short8;
typedef __attribute__((ext_vector_type(4))) float f32x4;
typedef __attribute__((ext_vector_type(16))) float f32x16;

#define GLDS16(g, l) __builtin_amdgcn_global_load_lds(                        \
    (const __attribute__((address_space(1))) unsigned int*)(g),               \
    (__attribute__((address_space(3))) unsigned int*)(l), 16, 0, 0)

static __device__ __forceinline__ unsigned short f2b(float f) {
  union { float f; unsigned u; } c; c.f = f;
  unsigned r = c.u + 0x7fffu + ((c.u >> 16) & 1u);
  return (unsigned short)(r >> 16);
}

// slot swizzle: element (row, c) of a [rows][1024] k-major array
static __device__ __forceinline__ int swzc(int row, int c) {
  return (c & ~31) | ((((c >> 3) & 3) ^ ((row >> 1) & 3)) << 3) | (c & 7);
}

// ---------------- cast resid f32 -> bf16 [8192][1024], slot-swizzled ----------------
__global__ void k_cast(const float* __restrict__ x, unsigned short* __restrict__ o, int n4) {
  int i = blockIdx.x * blockDim.x + threadIdx.x;
  if (i >= n4) return;
  float4 v = reinterpret_cast<const float4*>(x)[i];
  ushort4 u;
  u.x = f2b(v.x); u.y = f2b(v.y); u.z = f2b(v.z); u.w = f2b(v.w);
  const int flat = i * 4;
  const int row = flat >> 10, c = flat & 1023;
  *reinterpret_cast<ushort4*>(&o[row * 1024 + swzc(row, c)]) = u;
}

// ---- w_q/w_k/w_v [16][1024][64] f32 -> W3t[(which*1024+h*64+d)][1024 m] bf16, swizzled ----
__global__ void k_trans_qkv(const float* __restrict__ wq, const float* __restrict__ wk,
                            const float* __restrict__ wv, unsigned short* __restrict__ o) {
  __shared__ float t[64][65];
  int blk = blockIdx.x;            // 3*16*16
  int mt = blk & 15;
  int h = (blk >> 4) & 15;
  int which = blk >> 8;
  const float* w = which == 0 ? wq : (which == 1 ? wk : wv);
  int tid = threadIdx.x;
  int m0 = mt * 64;
  #pragma unroll
  for (int rep = 0; rep < 16; ++rep) {
    int idx = rep * 256 + tid;
    int r = idx >> 6, c = idx & 63;
    t[r][c] = w[(h * 1024 + m0 + r) * 64 + c];
  }
  __syncthreads();
  #pragma unroll
  for (int rep = 0; rep < 16; ++rep) {
    int idx = rep * 256 + tid;
    int dr = idx >> 6, mc = idx & 63;
    const int row = which * 1024 + h * 64 + dr;
    o[row * 1024 + swzc(dr, m0 + mc)] = f2b(t[mc][dr]);
  }
}

// ---- w_o [1024 k][1024 m] f32 -> WoT[m][k] bf16, swizzled ----
__global__ void k_trans_wo(const float* __restrict__ wo, unsigned short* __restrict__ o) {
  __shared__ float t[64][65];
  int blk = blockIdx.x;            // 256
  int mt = blk & 15, kt = blk >> 4;
  int tid = threadIdx.x;
  int k0 = kt * 64, m0 = mt * 64;
  #pragma unroll
  for (int rep = 0; rep < 16; ++rep) {
    int idx = rep * 256 + tid;
    int r = idx >> 6, c = idx & 63;
    t[r][c] = wo[(k0 + r) * 1024 + m0 + c];
  }
  __syncthreads();
  #pragma unroll
  for (int rep = 0; rep < 16; ++rep) {
    int idx = rep * 256 + tid;
    int r = idx >> 6, c = idx & 63;
    o[(m0 + r) * 1024 + swzc(r, k0 + c)] = f2b(t[c][r]);
  }
}

// ---------------- 128x128 bf16 GEMM -> Q / Kc / Vc (fused N=3072) ----------------
// Issue-ahead double-buffered k-loop (1 barrier/step, vmcnt(0) after MFMAs).
// Swizzled ds_reads (conflict-free). Q/K blocks use swapped mfma(b,a) -> ushort4 stores.
__global__ __launch_bounds__(256) void k_gemm_qkv(const unsigned short* __restrict__ A,
                                                  const unsigned short* __restrict__ Bt,
                                                  unsigned short* __restrict__ Qb,
                                                  unsigned short* __restrict__ Kc,
                                                  unsigned short* __restrict__ Vc) {
  __shared__ unsigned short As[2][128 * 32];
  __shared__ unsigned short Bs[2][128 * 32];
  const int bm = blockIdx.x, bn = blockIdx.y;
  const int tid = threadIdx.x;
  const int lane = tid & 63, wid = tid >> 6;
  const int wr = wid >> 1, wc = wid & 1;
  const int fr = lane & 15, fq = lane >> 4;
  const int which = bn >> 3;                    // 0:Q 1:K 2:V (block-uniform)

  f32x4 acc[4][4];
  #pragma unroll
  for (int i = 0; i < 4; ++i)
    #pragma unroll
    for (int n = 0; n < 4; ++n) acc[i][n] = f32x4{0.f, 0.f, 0.f, 0.f};

  const int arow = tid >> 2, acol = (tid & 3) * 8;
  const int lds0 = tid * 8, lds1 = tid * 8 + 2048;
  const unsigned short* aG0 = A + (bm * 128 + arow) * 1024 + acol;
  const unsigned short* aG1 = A + (bm * 128 + arow + 64) * 1024 + acol;
  const unsigned short* bG0 = Bt + (bn * 128 + arow) * 1024 + acol;
  const unsigned short* bG1 = Bt + (bn * 128 + arow + 64) * 1024 + acol;

  const int rowA = (wr * 64 + fr) * 32;
  const int rowB = (wc * 64 + fr) * 32;
  const int slot = ((fq ^ ((fr >> 1) & 3)) << 3);   // swizzled 16B slot

  GLDS16(aG0, As[0] + lds0);
  GLDS16(aG1, As[0] + lds1);
  GLDS16(bG0, Bs[0] + lds0);
  GLDS16(bG1, Bs[0] + lds1);
  asm volatile("s_waitcnt vmcnt(0)" ::: "memory");
  __syncthreads();

  for (int k0 = 0; k0 < 1024; k0 += 32) {
    const int cur = (k0 >> 5) & 1;
    if (k0 + 32 < 1024) {
      GLDS16(aG0 + k0 + 32, As[cur ^ 1] + lds0);
      GLDS16(aG1 + k0 + 32, As[cur ^ 1] + lds1);
      GLDS16(bG0 + k0 + 32, Bs[cur ^ 1] + lds0);
      GLDS16(bG1 + k0 + 32, Bs[cur ^ 1] + lds1);
    }
    short8 a[4], b[4];
    #pragma unroll
    for (int i = 0; i < 4; ++i)
      a[i] = *reinterpret_cast<const short8*>(As[cur] + rowA + i * 512 + slot);
    #pragma unroll
    for (int n = 0; n < 4; ++n)
      b[n] = *reinterpret_cast<const short8*>(Bs[cur] + rowB + n * 512 + slot);
    if (which == 2) {
      #pragma unroll
      for (int i = 0; i < 4; ++i)
        #pragma unroll
        for (int n = 0; n < 4; ++n)
          acc[i][n] = __builtin_amdgcn_mfma_f32_16x16x32_bf16(a[i], b[n], acc[i][n], 0, 0, 0);
    } else {
      #pragma unroll
      for (int i = 0; i < 4; ++i)
        #pragma unroll
        for (int n = 0; n < 4; ++n)   // swapped: j walks d
          acc[i][n] = __builtin_amdgcn_mfma_f32_16x16x32_bf16(b[n], a[i], acc[i][n], 0, 0, 0);
    }
    asm volatile("s_waitcnt vmcnt(0)" ::: "memory");
    __syncthreads();
  }

  if (which == 2) {
    // V epilogue: j walks s. col -> (h,d); element (d, kk=s&31) in swizzled blob.
    const int colb = bn * 128 + wc * 64 + fr - 2048;
    const int rowb = bm * 128 + wr * 64 + fq * 4;
    #pragma unroll
    for (int n = 0; n < 4; ++n) {
      const int rc = colb + n * 16;
      const int h = rc >> 6, d = rc & 63;
      #pragma unroll
      for (int i = 0; i < 4; ++i) {
        const int row = rowb + i * 16;
        const int b_ = row >> 11, s = row & 2047;
        const int bh = b_ * 16 + h;
        const int c = s >> 5, kk = s & 31;
        const int r = d >> 1;
        const int sl = (((d & 1) * 4 + (kk >> 3)) ^ (r & 7));
        ushort4 v;
        v.x = f2b(acc[i][n][0]); v.y = f2b(acc[i][n][1]);
        v.z = f2b(acc[i][n][2]); v.w = f2b(acc[i][n][3]);
        *reinterpret_cast<ushort4*>(
            &Vc[((size_t)(bh * 64 + c)) * 2048 + r * 64 + sl * 8 + (kk & 7)]) = v;
      }
    }
  } else {
    const float CS = 0.125f * 1.44269504088896340736f;
    const int rowS = bm * 128 + wr * 64 + fr;          // s base (+i*16)
    const int cold = bn * 128 + wc * 64 + fq * 4;      // col base (+n*16)
    #pragma unroll
    for (int i = 0; i < 4; ++i) {
      const int S = rowS + i * 16;
      const int b_ = S >> 11, s = S & 2047;
      #pragma unroll
      for (int n = 0; n < 4; ++n) {
        const int col = cold + n * 16;
        const int rc = col & 1023;
        const int h = rc >> 6, d0 = rc & 63;
        const int bh = b_ * 16 + h;
        if (which == 0) {
          ushort4 u;
          u.x = f2b(acc[i][n][0] * CS); u.y = f2b(acc[i][n][1] * CS);
          u.z = f2b(acc[i][n][2] * CS); u.w = f2b(acc[i][n][3] * CS);
          *reinterpret_cast<ushort4*>(&Qb[((size_t)bh * 2048 + s) * 64 + d0]) = u;
        } else {
          const int c = s >> 5, r = s & 31;
          const int dsw0 = (((d0 >> 3) ^ (r & 7)) << 3) | (d0 & 7);
          ushort4 u;
          u.x = f2b(acc[i][n][0]); u.y = f2b(acc[i][n][1]);
          u.z = f2b(acc[i][n][2]); u.w = f2b(acc[i][n][3]);
          *reinterpret_cast<ushort4*>(
              &Kc[(((size_t)(bh * 64 + c)) * 32 + r) * 64 + dsw0]) = u;
        }
      }
    }
  }
}

// ---------------- causal flash attention, LDS-staged K/V, swapped-QK^T 32x32 ----------------

static __device__ __forceinline__ f32x16 mfma32(short8 a, short8 b, f32x16 c) {
  return __builtin_amdgcn_mfma_f32_32x32x16_bf16(a, b, c, 0, 0, 0);
}

template<bool MASKED>
static __device__ __forceinline__ void compute_chunk(
    const unsigned short* __restrict__ Kl, const unsigned short* __restrict__ Vl,
    int q, int hi,
    const short8& Qf0, const short8& Qf1, const short8& Qf2, const short8& Qf3,
    f32x16& accA, f32x16& accB, float& lsum) {
  const int qs = q & 7;
  const short8 kf0 = *reinterpret_cast<const short8*>(Kl + q * 64 + (((0 + hi) ^ qs) << 3));
  const short8 kf1 = *reinterpret_cast<const short8*>(Kl + q * 64 + (((2 + hi) ^ qs) << 3));
  const short8 kf2 = *reinterpret_cast<const short8*>(Kl + q * 64 + (((4 + hi) ^ qs) << 3));
  const short8 kf3 = *reinterpret_cast<const short8*>(Kl + q * 64 + (((6 + hi) ^ qs) << 3));
  const int vr = q >> 1, vs = (q & 1) * 4, vw = vr & 7;
  const short8 v00 = *reinterpret_cast<const short8*>(Vl + vr * 64 + (((vs + hi) ^ vw) << 3));
  const short8 v01 = *reinterpret_cast<const short8*>(Vl + vr * 64 + (((vs + 2 + hi) ^ vw) << 3));
  const short8 v10 = *reinterpret_cast<const short8*>(Vl + (vr + 16) * 64 + (((vs + hi) ^ vw) << 3));
  const short8 v11 = *reinterpret_cast<const short8*>(Vl + (vr + 16) * 64 + (((vs + 2 + hi) ^ vw) << 3));

  f32x16 s = {0.f,0.f,0.f,0.f,0.f,0.f,0.f,0.f,0.f,0.f,0.f,0.f,0.f,0.f,0.f,0.f};
  s = mfma32(kf0, Qf0, s);
  s = mfma32(kf1, Qf1, s);
  s = mfma32(kf2, Qf2, s);
  s = mfma32(kf3, Qf3, s);

  float p[16];
  #pragma unroll
  for (int r = 0; r < 16; ++r) {
    if (MASKED) {
      const int kr = (r & 3) + 8 * (r >> 2) + 4 * hi;
      p[r] = (kr <= q) ? __builtin_amdgcn_exp2f(s[r]) : 0.f;
    } else {
      p[r] = __builtin_amdgcn_exp2f(s[r]);
    }
  }
  float t0 = (p[0] + p[1]) + (p[2] + p[3]);
  float t1 = (p[4] + p[5]) + (p[6] + p[7]);
  float t2 = (p[8] + p[9]) + (p[10] + p[11]);
  float t3 = (p[12] + p[13]) + (p[14] + p[15]);
  lsum += (t0 + t1) + (t2 + t3);

  unsigned W[8], X[8];
  #pragma unroll
  for (int i = 0; i < 8; ++i)
    asm("v_cvt_pk_bf16_f32 %0, %1, %2" : "=v"(W[i]) : "v"(p[2 * i]), "v"(p[2 * i + 1]));
  #pragma unroll
  for (int i = 0; i < 8; ++i) X[i] = __shfl_xor(W[i], 32);

  union { unsigned u[4]; short8 v; } fa0, fa1;
  fa0.u[0] = hi ? X[2] : W[0];
  fa0.u[1] = hi ? X[3] : W[1];
  fa0.u[2] = hi ? W[2] : X[0];
  fa0.u[3] = hi ? W[3] : X[1];
  fa1.u[0] = hi ? X[6] : W[4];
  fa1.u[1] = hi ? X[7] : W[5];
  fa1.u[2] = hi ? W[6] : X[4];
  fa1.u[3] = hi ? W[7] : X[5];

  accA = mfma32(fa0.v, v00, accA);
  accA = mfma32(fa1.v, v01, accA);
  accB = mfma32(fa0.v, v10, accB);
  accB = mfma32(fa1.v, v11, accB);
}

// Zb is written slot-swizzled (it feeds k_gemm_out's A-staging).
static __device__ __forceinline__ void store_tile(unsigned short* __restrict__ Zb,
    int b_, int h, int q0, int q, int hi,
    const f32x16& a0, const f32x16& a1, float lsum) {
  const float lt = lsum + __shfl_xor(lsum, 32);
  const float rl = 1.f / lt;
  #pragma unroll
  for (int r = 0; r < 16; ++r) {
    const int qr = (r & 3) + 8 * (r >> 2) + 4 * hi;
    const float rlr = __shfl(rl, qr);
    const int row = b_ * 2048 + q0 + qr;
    const int sl = (((q >> 3) ^ ((qr >> 1) & 3)) << 3) + (q & 7);
    unsigned short* dst = Zb + (size_t)row * 1024 + h * 64;
    dst[sl]      = f2b(a0[r] * rlr);
    dst[32 + sl] = f2b(a1[r] * rlr);
  }
}

__global__ __launch_bounds__(256, 2) void k_attn(const unsigned short* __restrict__ Qb,
                                                 const unsigned short* __restrict__ Kc,
                                                 const unsigned short* __restrict__ Vc,
                                                 unsigned short* __restrict__ Zb) {
  __shared__ __align__(16) unsigned short Kbuf[2][2048];
  __shared__ __align__(16) unsigned short Vbuf[2][2048];
  const int tid = threadIdx.x;
  const int lane = tid & 63, w = tid >> 6;
  const int q = lane & 31, hi = lane >> 5;
  const int bid = blockIdx.x;                    // 0..511
  const int bh = (bid & 7) * 8 + ((bid >> 3) & 7);
  const int P1 = bid >> 6;                       // 0..7 -> pair (P1, 15-P1)
  const int b_ = bh >> 4, h = bh & 15;

  const unsigned short* Qbh = Qb + (size_t)bh * 2048 * 64;
  const unsigned short* Kch = Kc + (size_t)bh * 64 * 2048;
  const unsigned short* Vch = Vc + (size_t)bh * 64 * 2048;

  #pragma unroll 1
  for (int t = 0; t < 2; ++t) {
    const int P = t ? (15 - P1) : P1;
    const int q0 = 128 * P + 32 * w;
    const int cmax = 4 * P + w;
    const int C = 4 * P + 4;

    const unsigned short* Qp = Qbh + (size_t)(q0 + q) * 64 + hi * 8;
    const short8 Qf0 = *reinterpret_cast<const short8*>(Qp);
    const short8 Qf1 = *reinterpret_cast<const short8*>(Qp + 16);
    const short8 Qf2 = *reinterpret_cast<const short8*>(Qp + 32);
    const short8 Qf3 = *reinterpret_cast<const short8*>(Qp + 48);

    f32x16 a0 = {0.f,0.f,0.f,0.f,0.f,0.f,0.f,0.f,0.f,0.f,0.f,0.f,0.f,0.f,0.f,0.f};
    f32x16 a1 = a0;
    float l = 0.f;

    GLDS16(Kch + tid * 8, &Kbuf[0][tid * 8]);
    GLDS16(Vch + tid * 8, &Vbuf[0][tid * 8]);

    for (int c = 0; c < C; ++c) {
      if (c + 1 < C) {
        const int par = (c + 1) & 1;
        GLDS16(Kch + (size_t)(c + 1) * 2048 + tid * 8, &Kbuf[par][tid * 8]);
        GLDS16(Vch + (size_t)(c + 1) * 2048 + tid * 8, &Vbuf[par][tid * 8]);
        asm volatile("s_waitcnt vmcnt(2)" ::: "memory");
      } else {
        asm volatile("s_waitcnt vmcnt(0)" ::: "memory");
      }
      __syncthreads();
      if (c <= cmax) {
        const int par = c & 1;
        if (c == cmax)
          compute_chunk<true>(Kbuf[par], Vbuf[par], q, hi, Qf0, Qf1, Qf2, Qf3, a0, a1, l);
        else
          compute_chunk<false>(Kbuf[par], Vbuf[par], q, hi, Qf0, Qf1, Qf2, Qf3, a0, a1, l);
      }
      __syncthreads();
    }
    store_tile(Zb, b_, h, q0, q, hi, a0, a1, l);
  }
}

// ---------------- 128x128 GEMM: out = Z @ Wo, dbuf + swizzled reads, float4 epilogue ----------------
__global__ __launch_bounds__(256) void k_gemm_out(const unsigned short* __restrict__ A,
                                                  const unsigned short* __restrict__ Bt,
                                                  float* __restrict__ Out) {
  __shared__ unsigned short As[2][128 * 32];
  __shared__ unsigned short Bs[2][128 * 32];
  const int bm = blockIdx.x, bn = blockIdx.y;
  const int tid = threadIdx.x;
  const int lane = tid & 63, wid = tid >> 6;
  const int wr = wid >> 1, wc = wid & 1;
  const int fr = lane & 15, fq = lane >> 4;

  f32x4 acc[4][4];
  #pragma unroll
  for (int i = 0; i < 4; ++i)
    #pragma unroll
    for (int n = 0; n < 4; ++n) acc[i][n] = f32x4{0.f, 0.f, 0.f, 0.f};

  const int arow = tid >> 2, acol = (tid & 3) * 8;
  const int lds0 = tid * 8, lds1 = tid * 8 + 2048;
  const unsigned short* aG0 = A + (bm * 128 + arow) * 1024 + acol;
  const unsigned short* aG1 = A + (bm * 128 + arow + 64) * 1024 + acol;
  const unsigned short* bG0 = Bt + (bn * 128 + arow) * 1024 + acol;
  const unsigned short* bG1 = Bt + (bn * 128 + arow + 64) * 1024 + acol;

  const int rowA = (wr * 64 + fr) * 32;
  const int rowB = (wc * 64 + fr) * 32;
  const int slot = ((fq ^ ((fr >> 1) & 3)) << 3);

  GLDS16(aG0, As[0] + lds0);
  GLDS16(aG1, As[0] + lds1);
  GLDS16(bG0, Bs[0] + lds0);
  GLDS16(bG1, Bs[0] + lds1);
  asm volatile("s_waitcnt vmcnt(0)" ::: "memory");
  __syncthreads();

  for (int k0 = 0; k0 < 1024; k0 += 32) {
    const int cur = (k0 >> 5) & 1;
    if (k0 + 32 < 1024) {
      GLDS16(aG0 + k0 + 32, As[cur ^ 1] + lds0);
      GLDS16(aG1 + k0 + 32, As[cur ^ 1] + lds1);
      GLDS16(bG0 + k0 + 32, Bs[cur ^ 1] + lds0);
      GLDS16(bG1 + k0 + 32, Bs[cur ^ 1] + lds1);
    }
    short8 a[4], b[4];
    #pragma unroll
    for (int i = 0; i < 4; ++i)
      a[i] = *reinterpret_cast<const short8*>(As[cur] + rowA + i * 512 + slot);
    #pragma unroll
    for (int n = 0; n < 4; ++n)
      b[n] = *reinterpret_cast<const short8*>(Bs[cur] + rowB + n * 512 + slot);
    #pragma unroll
    for (int i = 0; i < 4; ++i)
      #pragma unroll
      for (int n = 0; n < 4; ++n)   // swapped: j walks the output-col dim
        acc[i][n] = __builtin_amdgcn_mfma_f32_16x16x32_bf16(b[n], a[i], acc[i][n], 0, 0, 0);
    asm volatile("s_waitcnt vmcnt(0)" ::: "memory");
    __syncthreads();
  }

  const int rowS = bm * 128 + wr * 64 + fr;
  const int cold = bn * 128 + wc * 64 + fq * 4;
  #pragma unroll
  for (int i = 0; i < 4; ++i) {
    const int S = rowS + i * 16;
    #pragma unroll
    for (int n = 0; n < 4; ++n) {
      const int m0 = cold + n * 16;
      float4 v;
      v.x = acc[i][n][0]; v.y = acc[i][n][1]; v.z = acc[i][n][2]; v.w = acc[i][n][3];
      *reinterpret_cast<float4*>(&Out[(size_t)S * 1024 + m0]) = v;
    }
  }
}

extern "C" void kernel_launch(void* const* d_in, const int* in_sizes, int n_in,
                              void* d_out, int out_size, void* d_ws, size_t ws_size,
                              hipStream_t stream) {
  const float* resid = (const float*)d_in[0];
  const float* w_q = (const float*)d_in[1];
  const float* w_k = (const float*)d_in[2];
  const float* w_v = (const float*)d_in[3];
  const float* w_o = (const float*)d_in[4];
  float* out = (float*)d_out;

  char* ws = (char*)d_ws;
  const size_t MB = 1u << 20;
  unsigned short* Xb = (unsigned short*)(ws);            // 16 MiB: resid bf16 swz; reused as Zb
  unsigned short* W3 = (unsigned short*)(ws + 16 * MB);  // 6 MiB : fused qkv B^T swz
  unsigned short* Wo = (unsigned short*)(ws + 22 * MB);  // 2 MiB : WoT swz
  unsigned short* Qb = (unsigned short*)(ws + 24 * MB);  // 16 MiB: Q [bh][s][d] (pre-scaled)
  unsigned short* Kc = (unsigned short*)(ws + 40 * MB);  // 16 MiB: K chunked+swizzled blobs
  unsigned short* Vc = (unsigned short*)(ws + 56 * MB);  // 16 MiB: V chunked+swizzled blobs
  unsigned short* Zb = Xb;                               // alias: Xb dead after k_gemm_qkv

  hipLaunchKernelGGL(k_cast, dim3(8192), dim3(256), 0, stream, resid, Xb, 8192 * 1024 / 4);
  hipLaunchKernelGGL(k_trans_qkv, dim3(768), dim3(256), 0, stream, w_q, w_k, w_v, W3);
  hipLaunchKernelGGL(k_trans_wo, dim3(256), dim3(256), 0, stream, w_o, Wo);
  hipLaunchKernelGGL(k_gemm_qkv, dim3(64, 24), dim3(256), 0, stream, Xb, W3, Qb, Kc, Vc);
  hipLaunchKernelGGL(k_attn, dim3(512), dim3(256), 0, stream, Qb, Kc, Vc, Zb);
  hipLaunchKernelGGL(k_gemm_out, dim3(64, 8), dim3(256), 0, stream, Zb, Wo, out);
}

// Round 14
// 168.561 us; speedup vs baseline: 1.1711x; 1.1711x over previous
//
#include <hip/hip_runtime.h>

// Attention_29583734734990 : resid[4,2048,1024] f32, w_q/k/v[16,1024,64], w_o[16,64,1024]
// out[4,2048,1024] f32.  bf16 MFMA pipeline (threshold is bf16-floor 3.14e-2).
//
// GEMM input arrays (Xb, W3, Wo, Zb) are stored SLOT-SWIZZLED: within each
// 32-element k-chunk, 16B slot index ^= ((row>>1)&3).  global_load_lds stages
// chunks linearly; LDS readers XOR the same involution (rule-21 both-sides).

typedef __attribute__((ext_vector_type(8))) short short8;
typedef __attribute__((ext_vector_type(4))) float f32x4;
typedef __attribute__((ext_vector_type(16))) float f32x16;

#define GLDS16(g, l) __builtin_amdgcn_global_load_lds(                        \
    (const __attribute__((address_space(1))) unsigned int*)(g),               \
    (__attribute__((address_space(3))) unsigned int*)(l), 16, 0, 0)

static __device__ __forceinline__ unsigned short f2b(float f) {
  union { float f; unsigned u; } c; c.f = f;
  unsigned r = c.u + 0x7fffu + ((c.u >> 16) & 1u);
  return (unsigned short)(r >> 16);
}

// slot swizzle: element (row, c) of a [rows][1024] k-major array
static __device__ __forceinline__ int swzc(int row, int c) {
  return (c & ~31) | ((((c >> 3) & 3) ^ ((row >> 1) & 3)) << 3) | (c & 7);
}

// ---------------- cast resid f32 -> bf16 [8192][1024], slot-swizzled ----------------
__global__ void k_cast(const float* __restrict__ x, unsigned short* __restrict__ o, int n4) {
  int i = blockIdx.x * blockDim.x + threadIdx.x;
  if (i >= n4) return;
  float4 v = reinterpret_cast<const float4*>(x)[i];
  ushort4 u;
  u.x = f2b(v.x); u.y = f2b(v.y); u.z = f2b(v.z); u.w = f2b(v.w);
  const int flat = i * 4;
  const int row = flat >> 10, c = flat & 1023;
  *reinterpret_cast<ushort4*>(&o[row * 1024 + swzc(row, c)]) = u;
}

// ---- w_q/w_k/w_v [16][1024][64] f32 -> W3t[(which*1024+h*64+d)][1024 m] bf16, swizzled ----
__global__ void k_trans_qkv(const float* __restrict__ wq, const float* __restrict__ wk,
                            const float* __restrict__ wv, unsigned short* __restrict__ o) {
  __shared__ float t[64][65];
  int blk = blockIdx.x;            // 3*16*16
  int mt = blk & 15;
  int h = (blk >> 4) & 15;
  int which = blk >> 8;
  const float* w = which == 0 ? wq : (which == 1 ? wk : wv);
  int tid = threadIdx.x;
  int m0 = mt * 64;
  #pragma unroll
  for (int rep = 0; rep < 16; ++rep) {
    int idx = rep * 256 + tid;
    int r = idx >> 6, c = idx & 63;
    t[r][c] = w[(h * 1024 + m0 + r) * 64 + c];
  }
  __syncthreads();
  #pragma unroll
  for (int rep = 0; rep < 16; ++rep) {
    int idx = rep * 256 + tid;
    int dr = idx >> 6, mc = idx & 63;
    const int row = which * 1024 + h * 64 + dr;
    o[row * 1024 + swzc(dr, m0 + mc)] = f2b(t[mc][dr]);
  }
}

// ---- w_o [1024 k][1024 m] f32 -> WoT[m][k] bf16, swizzled ----
__global__ void k_trans_wo(const float* __restrict__ wo, unsigned short* __restrict__ o) {
  __shared__ float t[64][65];
  int blk = blockIdx.x;            // 256
  int mt = blk & 15, kt = blk >> 4;
  int tid = threadIdx.x;
  int k0 = kt * 64, m0 = mt * 64;
  #pragma unroll
  for (int rep = 0; rep < 16; ++rep) {
    int idx = rep * 256 + tid;
    int r = idx >> 6, c = idx & 63;
    t[r][c] = wo[(k0 + r) * 1024 + m0 + c];
  }
  __syncthreads();
  #pragma unroll
  for (int rep = 0; rep < 16; ++rep) {
    int idx = rep * 256 + tid;
    int r = idx >> 6, c = idx & 63;
    o[(m0 + r) * 1024 + swzc(r, k0 + c)] = f2b(t[c][r]);
  }
}

// ---------------- 128x128 bf16 GEMM -> Q / Kc / Vc (fused N=3072) ----------------
// r11 schedule (stage -> vmcnt(0) -> barrier -> compute -> barrier), BK=64 via two
// 32-col LDS planes per step (16 steps), swizzled conflict-free ds_reads.
__global__ __launch_bounds__(256) void k_gemm_qkv(const unsigned short* __restrict__ A,
                                                  const unsigned short* __restrict__ Bt,
                                                  unsigned short* __restrict__ Qb,
                                                  unsigned short* __restrict__ Kc,
                                                  unsigned short* __restrict__ Vc) {
  __shared__ unsigned short As[2][128 * 32];
  __shared__ unsigned short Bs[2][128 * 32];
  const int bm = blockIdx.x, bn = blockIdx.y;
  const int tid = threadIdx.x;
  const int lane = tid & 63, wid = tid >> 6;
  const int wr = wid >> 1, wc = wid & 1;
  const int fr = lane & 15, fq = lane >> 4;

  f32x4 acc[4][4];
  #pragma unroll
  for (int i = 0; i < 4; ++i)
    #pragma unroll
    for (int n = 0; n < 4; ++n) acc[i][n] = f32x4{0.f, 0.f, 0.f, 0.f};

  const int arow = tid >> 2, acol = (tid & 3) * 8;
  const int lds0 = tid * 8, lds1 = (tid + 256) * 8;
  const unsigned short* aG0 = A + (bm * 128 + arow) * 1024 + acol;
  const unsigned short* aG1 = A + (bm * 128 + arow + 64) * 1024 + acol;
  const unsigned short* bG0 = Bt + (bn * 128 + arow) * 1024 + acol;
  const unsigned short* bG1 = Bt + (bn * 128 + arow + 64) * 1024 + acol;

  const int rowA = (wr * 64 + fr) * 32;
  const int rowB = (wc * 64 + fr) * 32;
  const int slot = ((fq ^ ((fr >> 1) & 3)) << 3);   // swizzled 16B slot

  for (int k0 = 0; k0 < 1024; k0 += 64) {
    __syncthreads();
    GLDS16(aG0 + k0,      As[0] + lds0);
    GLDS16(aG1 + k0,      As[0] + lds1);
    GLDS16(aG0 + k0 + 32, As[1] + lds0);
    GLDS16(aG1 + k0 + 32, As[1] + lds1);
    GLDS16(bG0 + k0,      Bs[0] + lds0);
    GLDS16(bG1 + k0,      Bs[0] + lds1);
    GLDS16(bG0 + k0 + 32, Bs[1] + lds0);
    GLDS16(bG1 + k0 + 32, Bs[1] + lds1);
    asm volatile("s_waitcnt vmcnt(0)" ::: "memory");
    __syncthreads();
    #pragma unroll
    for (int p = 0; p < 2; ++p) {
      short8 a[4], b[4];
      #pragma unroll
      for (int i = 0; i < 4; ++i)
        a[i] = *reinterpret_cast<const short8*>(As[p] + rowA + i * 512 + slot);
      #pragma unroll
      for (int n = 0; n < 4; ++n)
        b[n] = *reinterpret_cast<const short8*>(Bs[p] + rowB + n * 512 + slot);
      #pragma unroll
      for (int i = 0; i < 4; ++i)
        #pragma unroll
        for (int n = 0; n < 4; ++n)
          acc[i][n] = __builtin_amdgcn_mfma_f32_16x16x32_bf16(a[i], b[n], acc[i][n], 0, 0, 0);
    }
  }

  const float CS = 0.125f * 1.44269504088896340736f;
  const int colb = bn * 128 + wc * 64 + fr;
  const int rowb = bm * 128 + wr * 64 + fq * 4;
  #pragma unroll
  for (int n = 0; n < 4; ++n) {
    const int col = colb + n * 16;
    const int which = col >> 10, rc = col & 1023;
    const int h = rc >> 6, d = rc & 63;
    #pragma unroll
    for (int i = 0; i < 4; ++i) {
      const int row = rowb + i * 16;
      const int b_ = row >> 11, s = row & 2047;
      const int bh = b_ * 16 + h;
      if (which == 2) {
        const int c = s >> 5, kk = s & 31;
        const int r = d >> 1;
        const int sl = (((d & 1) * 4 + (kk >> 3)) ^ (r & 7));
        ushort4 v;
        v.x = f2b(acc[i][n][0]); v.y = f2b(acc[i][n][1]);
        v.z = f2b(acc[i][n][2]); v.w = f2b(acc[i][n][3]);
        *reinterpret_cast<ushort4*>(
            &Vc[((size_t)(bh * 64 + c)) * 2048 + r * 64 + sl * 8 + (kk & 7)]) = v;
      } else if (which == 1) {
        #pragma unroll
        for (int j = 0; j < 4; ++j) {
          const int ss = s + j;
          const int c = ss >> 5, r = ss & 31;
          const int dsw = (((d >> 3) ^ (r & 7)) << 3) | (d & 7);
          Kc[(((size_t)(bh * 64 + c)) * 32 + r) * 64 + dsw] = f2b(acc[i][n][j]);
        }
      } else {
        unsigned short* dst = Qb + ((size_t)bh * 2048 + s) * 64 + d;
        #pragma unroll
        for (int j = 0; j < 4; ++j) dst[j * 64] = f2b(acc[i][n][j] * CS);
      }
    }
  }
}

// ---------------- causal flash attention, LDS-staged K/V, swapped-QK^T 32x32 ----------------

static __device__ __forceinline__ f32x16 mfma32(short8 a, short8 b, f32x16 c) {
  return __builtin_amdgcn_mfma_f32_32x32x16_bf16(a, b, c, 0, 0, 0);
}

template<bool MASKED>
static __device__ __forceinline__ void compute_chunk(
    const unsigned short* __restrict__ Kl, const unsigned short* __restrict__ Vl,
    int q, int hi,
    const short8& Qf0, const short8& Qf1, const short8& Qf2, const short8& Qf3,
    f32x16& accA, f32x16& accB, float& lsum) {
  const int qs = q & 7;
  const short8 kf0 = *reinterpret_cast<const short8*>(Kl + q * 64 + (((0 + hi) ^ qs) << 3));
  const short8 kf1 = *reinterpret_cast<const short8*>(Kl + q * 64 + (((2 + hi) ^ qs) << 3));
  const short8 kf2 = *reinterpret_cast<const short8*>(Kl + q * 64 + (((4 + hi) ^ qs) << 3));
  const short8 kf3 = *reinterpret_cast<const short8*>(Kl + q * 64 + (((6 + hi) ^ qs) << 3));
  const int vr = q >> 1, vs = (q & 1) * 4, vw = vr & 7;
  const short8 v00 = *reinterpret_cast<const short8*>(Vl + vr * 64 + (((vs + hi) ^ vw) << 3));
  const short8 v01 = *reinterpret_cast<const short8*>(Vl + vr * 64 + (((vs + 2 + hi) ^ vw) << 3));
  const short8 v10 = *reinterpret_cast<const short8*>(Vl + (vr + 16) * 64 + (((vs + hi) ^ vw) << 3));
  const short8 v11 = *reinterpret_cast<const short8*>(Vl + (vr + 16) * 64 + (((vs + 2 + hi) ^ vw) << 3));

  f32x16 s = {0.f,0.f,0.f,0.f,0.f,0.f,0.f,0.f,0.f,0.f,0.f,0.f,0.f,0.f,0.f,0.f};
  s = mfma32(kf0, Qf0, s);
  s = mfma32(kf1, Qf1, s);
  s = mfma32(kf2, Qf2, s);
  s = mfma32(kf3, Qf3, s);

  float p[16];
  #pragma unroll
  for (int r = 0; r < 16; ++r) {
    if (MASKED) {
      const int kr = (r & 3) + 8 * (r >> 2) + 4 * hi;
      p[r] = (kr <= q) ? __builtin_amdgcn_exp2f(s[r]) : 0.f;
    } else {
      p[r] = __builtin_amdgcn_exp2f(s[r]);
    }
  }
  float t0 = (p[0] + p[1]) + (p[2] + p[3]);
  float t1 = (p[4] + p[5]) + (p[6] + p[7]);
  float t2 = (p[8] + p[9]) + (p[10] + p[11]);
  float t3 = (p[12] + p[13]) + (p[14] + p[15]);
  lsum += (t0 + t1) + (t2 + t3);

  unsigned W[8], X[8];
  #pragma unroll
  for (int i = 0; i < 8; ++i)
    asm("v_cvt_pk_bf16_f32 %0, %1, %2" : "=v"(W[i]) : "v"(p[2 * i]), "v"(p[2 * i + 1]));
  #pragma unroll
  for (int i = 0; i < 8; ++i) X[i] = __shfl_xor(W[i], 32);

  union { unsigned u[4]; short8 v; } fa0, fa1;
  fa0.u[0] = hi ? X[2] : W[0];
  fa0.u[1] = hi ? X[3] : W[1];
  fa0.u[2] = hi ? W[2] : X[0];
  fa0.u[3] = hi ? W[3] : X[1];
  fa1.u[0] = hi ? X[6] : W[4];
  fa1.u[1] = hi ? X[7] : W[5];
  fa1.u[2] = hi ? W[6] : X[4];
  fa1.u[3] = hi ? W[7] : X[5];

  accA = mfma32(fa0.v, v00, accA);
  accA = mfma32(fa1.v, v01, accA);
  accB = mfma32(fa0.v, v10, accB);
  accB = mfma32(fa1.v, v11, accB);
}

// Zb is written slot-swizzled (it feeds k_gemm_out's A-staging).
static __device__ __forceinline__ void store_tile(unsigned short* __restrict__ Zb,
    int b_, int h, int q0, int q, int hi,
    const f32x16& a0, const f32x16& a1, float lsum) {
  const float lt = lsum + __shfl_xor(lsum, 32);
  const float rl = 1.f / lt;
  #pragma unroll
  for (int r = 0; r < 16; ++r) {
    const int qr = (r & 3) + 8 * (r >> 2) + 4 * hi;
    const float rlr = __shfl(rl, qr);
    const int row = b_ * 2048 + q0 + qr;
    const int sl = (((q >> 3) ^ ((qr >> 1) & 3)) << 3) + (q & 7);
    unsigned short* dst = Zb + (size_t)row * 1024 + h * 64;
    dst[sl]      = f2b(a0[r] * rlr);
    dst[32 + sl] = f2b(a1[r] * rlr);
  }
}

__global__ __launch_bounds__(256, 2) void k_attn(const unsigned short* __restrict__ Qb,
                                                 const unsigned short* __restrict__ Kc,
                                                 const unsigned short* __restrict__ Vc,
                                                 unsigned short* __restrict__ Zb) {
  __shared__ __align__(16) unsigned short Kbuf[2][2048];
  __shared__ __align__(16) unsigned short Vbuf[2][2048];
  const int tid = threadIdx.x;
  const int lane = tid & 63, w = tid >> 6;
  const int q = lane & 31, hi = lane >> 5;
  const int bid = blockIdx.x;                    // 0..511
  const int bh = (bid & 7) * 8 + ((bid >> 3) & 7);
  const int P1 = bid >> 6;                       // 0..7 -> pair (P1, 15-P1)
  const int b_ = bh >> 4, h = bh & 15;

  const unsigned short* Qbh = Qb + (size_t)bh * 2048 * 64;
  const unsigned short* Kch = Kc + (size_t)bh * 64 * 2048;
  const unsigned short* Vch = Vc + (size_t)bh * 64 * 2048;

  #pragma unroll 1
  for (int t = 0; t < 2; ++t) {
    const int P = t ? (15 - P1) : P1;
    const int q0 = 128 * P + 32 * w;
    const int cmax = 4 * P + w;
    const int C = 4 * P + 4;

    const unsigned short* Qp = Qbh + (size_t)(q0 + q) * 64 + hi * 8;
    const short8 Qf0 = *reinterpret_cast<const short8*>(Qp);
    const short8 Qf1 = *reinterpret_cast<const short8*>(Qp + 16);
    const short8 Qf2 = *reinterpret_cast<const short8*>(Qp + 32);
    const short8 Qf3 = *reinterpret_cast<const short8*>(Qp + 48);

    f32x16 a0 = {0.f,0.f,0.f,0.f,0.f,0.f,0.f,0.f,0.f,0.f,0.f,0.f,0.f,0.f,0.f,0.f};
    f32x16 a1 = a0;
    float l = 0.f;

    GLDS16(Kch + tid * 8, &Kbuf[0][tid * 8]);
    GLDS16(Vch + tid * 8, &Vbuf[0][tid * 8]);

    for (int c = 0; c < C; ++c) {
      if (c + 1 < C) {
        const int par = (c + 1) & 1;
        GLDS16(Kch + (size_t)(c + 1) * 2048 + tid * 8, &Kbuf[par][tid * 8]);
        GLDS16(Vch + (size_t)(c + 1) * 2048 + tid * 8, &Vbuf[par][tid * 8]);
        asm volatile("s_waitcnt vmcnt(2)" ::: "memory");
      } else {
        asm volatile("s_waitcnt vmcnt(0)" ::: "memory");
      }
      __syncthreads();
      if (c <= cmax) {
        const int par = c & 1;
        if (c == cmax)
          compute_chunk<true>(Kbuf[par], Vbuf[par], q, hi, Qf0, Qf1, Qf2, Qf3, a0, a1, l);
        else
          compute_chunk<false>(Kbuf[par], Vbuf[par], q, hi, Qf0, Qf1, Qf2, Qf3, a0, a1, l);
      }
      __syncthreads();
    }
    store_tile(Zb, b_, h, q0, q, hi, a0, a1, l);
  }
}

// ---------------- 128x128 GEMM: out = Z @ Wo (BK=64 two-plane, r11 schedule) ----------------
__global__ __launch_bounds__(256) void k_gemm_out(const unsigned short* __restrict__ A,
                                                  const unsigned short* __restrict__ Bt,
                                                  float* __restrict__ Out) {
  __shared__ unsigned short As[2][128 * 32];
  __shared__ unsigned short Bs[2][128 * 32];
  const int bm = blockIdx.x, bn = blockIdx.y;
  const int tid = threadIdx.x;
  const int lane = tid & 63, wid = tid >> 6;
  const int wr = wid >> 1, wc = wid & 1;
  const int fr = lane & 15, fq = lane >> 4;

  f32x4 acc[4][4];
  #pragma unroll
  for (int i = 0; i < 4; ++i)
    #pragma unroll
    for (int n = 0; n < 4; ++n) acc[i][n] = f32x4{0.f, 0.f, 0.f, 0.f};

  const int arow = tid >> 2, acol = (tid & 3) * 8;
  const int lds0 = tid * 8, lds1 = (tid + 256) * 8;
  const unsigned short* aG0 = A + (bm * 128 + arow) * 1024 + acol;
  const unsigned short* aG1 = A + (bm * 128 + arow + 64) * 1024 + acol;
  const unsigned short* bG0 = Bt + (bn * 128 + arow) * 1024 + acol;
  const unsigned short* bG1 = Bt + (bn * 128 + arow + 64) * 1024 + acol;

  const int rowA = (wr * 64 + fr) * 32;
  const int rowB = (wc * 64 + fr) * 32;
  const int slot = ((fq ^ ((fr >> 1) & 3)) << 3);

  for (int k0 = 0; k0 < 1024; k0 += 64) {
    __syncthreads();
    GLDS16(aG0 + k0,      As[0] + lds0);
    GLDS16(aG1 + k0,      As[0] + lds1);
    GLDS16(aG0 + k0 + 32, As[1] + lds0);
    GLDS16(aG1 + k0 + 32, As[1] + lds1);
    GLDS16(bG0 + k0,      Bs[0] + lds0);
    GLDS16(bG1 + k0,      Bs[0] + lds1);
    GLDS16(bG0 + k0 + 32, Bs[1] + lds0);
    GLDS16(bG1 + k0 + 32, Bs[1] + lds1);
    asm volatile("s_waitcnt vmcnt(0)" ::: "memory");
    __syncthreads();
    #pragma unroll
    for (int p = 0; p < 2; ++p) {
      short8 a[4], b[4];
      #pragma unroll
      for (int i = 0; i < 4; ++i)
        a[i] = *reinterpret_cast<const short8*>(As[p] + rowA + i * 512 + slot);
      #pragma unroll
      for (int n = 0; n < 4; ++n)
        b[n] = *reinterpret_cast<const short8*>(Bs[p] + rowB + n * 512 + slot);
      #pragma unroll
      for (int i = 0; i < 4; ++i)
        #pragma unroll
        for (int n = 0; n < 4; ++n)
          acc[i][n] = __builtin_amdgcn_mfma_f32_16x16x32_bf16(a[i], b[n], acc[i][n], 0, 0, 0);
    }
  }

  const int colb = bn * 128 + wc * 64 + fr;
  const int rowb = bm * 128 + wr * 64 + fq * 4;
  #pragma unroll
  for (int n = 0; n < 4; ++n) {
    const int col = colb + n * 16;
    #pragma unroll
    for (int i = 0; i < 4; ++i) {
      const int row = rowb + i * 16;
      #pragma unroll
      for (int j = 0; j < 4; ++j) Out[(size_t)(row + j) * 1024 + col] = acc[i][n][j];
    }
  }
}

extern "C" void kernel_launch(void* const* d_in, const int* in_sizes, int n_in,
                              void* d_out, int out_size, void* d_ws, size_t ws_size,
                              hipStream_t stream) {
  const float* resid = (const float*)d_in[0];
  const float* w_q = (const float*)d_in[1];
  const float* w_k = (const float*)d_in[2];
  const float* w_v = (const float*)d_in[3];
  const float* w_o = (const float*)d_in[4];
  float* out = (float*)d_out;

  char* ws = (char*)d_ws;
  const size_t MB = 1u << 20;
  unsigned short* Xb = (unsigned short*)(ws);            // 16 MiB: resid bf16 swz; reused as Zb
  unsigned short* W3 = (unsigned short*)(ws + 16 * MB);  // 6 MiB : fused qkv B^T swz
  unsigned short* Wo = (unsigned short*)(ws + 22 * MB);  // 2 MiB : WoT swz
  unsigned short* Qb = (unsigned short*)(ws + 24 * MB);  // 16 MiB: Q [bh][s][d] (pre-scaled)
  unsigned short* Kc = (unsigned short*)(ws + 40 * MB);  // 16 MiB: K chunked+swizzled blobs
  unsigned short* Vc = (unsigned short*)(ws + 56 * MB);  // 16 MiB: V chunked+swizzled blobs
  unsigned short* Zb = Xb;                               // alias: Xb dead after k_gemm_qkv

  hipLaunchKernelGGL(k_cast, dim3(8192), dim3(256), 0, stream, resid, Xb, 8192 * 1024 / 4);
  hipLaunchKernelGGL(k_trans_qkv, dim3(768), dim3(256), 0, stream, w_q, w_k, w_v, W3);
  hipLaunchKernelGGL(k_trans_wo, dim3(256), dim3(256), 0, stream, w_o, Wo);
  hipLaunchKernelGGL(k_gemm_qkv, dim3(64, 24), dim3(256), 0, stream, Xb, W3, Qb, Kc, Vc);
  hipLaunchKernelGGL(k_attn, dim3(512), dim3(256), 0, stream, Qb, Kc, Vc, Zb);
  hipLaunchKernelGGL(k_gemm_out, dim3(64, 8), dim3(256), 0, stream, Zb, Wo, out);
}

// Round 15
// 165.724 us; speedup vs baseline: 1.1911x; 1.0171x over previous
//
#include <hip/hip_runtime.h>

// Attention_29583734734990 : resid[4,2048,1024] f32, w_q/k/v[16,1024,64], w_o[16,64,1024]
// out[4,2048,1024] f32.  bf16 MFMA pipeline (threshold is bf16-floor 3.14e-2).
//
// GEMM input arrays (Xb, W3, Wo, Zb) are stored SLOT-SWIZZLED: within each
// 32-element k-chunk, 16B slot index ^= ((row>>1)&3).  global_load_lds stages
// chunks linearly; LDS readers XOR the same involution (rule-21 both-sides).

typedef __attribute__((ext_vector_type(8))) short short8;
typedef __attribute__((ext_vector_type(4))) float f32x4;
typedef __attribute__((ext_vector_type(16))) float f32x16;

#define GLDS16(g, l) __builtin_amdgcn_global_load_lds(                        \
    (const __attribute__((address_space(1))) unsigned int*)(g),               \
    (__attribute__((address_space(3))) unsigned int*)(l), 16, 0, 0)

static __device__ __forceinline__ unsigned short f2b(float f) {
  union { float f; unsigned u; } c; c.f = f;
  unsigned r = c.u + 0x7fffu + ((c.u >> 16) & 1u);
  return (unsigned short)(r >> 16);
}

// slot swizzle: element (row, c) of a [rows][1024] k-major array
static __device__ __forceinline__ int swzc(int row, int c) {
  return (c & ~31) | ((((c >> 3) & 3) ^ ((row >> 1) & 3)) << 3) | (c & 7);
}

// ---------------- cast resid f32 -> bf16 [8192][1024], slot-swizzled ----------------
__global__ void k_cast(const float* __restrict__ x, unsigned short* __restrict__ o, int n4) {
  int i = blockIdx.x * blockDim.x + threadIdx.x;
  if (i >= n4) return;
  float4 v = reinterpret_cast<const float4*>(x)[i];
  ushort4 u;
  u.x = f2b(v.x); u.y = f2b(v.y); u.z = f2b(v.z); u.w = f2b(v.w);
  const int flat = i * 4;
  const int row = flat >> 10, c = flat & 1023;
  *reinterpret_cast<ushort4*>(&o[row * 1024 + swzc(row, c)]) = u;
}

// ---- w_q/w_k/w_v [16][1024][64] f32 -> W3t[(which*1024+h*64+d)][1024 m] bf16, swizzled ----
__global__ void k_trans_qkv(const float* __restrict__ wq, const float* __restrict__ wk,
                            const float* __restrict__ wv, unsigned short* __restrict__ o) {
  __shared__ float t[64][65];
  int blk = blockIdx.x;            // 3*16*16
  int mt = blk & 15;
  int h = (blk >> 4) & 15;
  int which = blk >> 8;
  const float* w = which == 0 ? wq : (which == 1 ? wk : wv);
  int tid = threadIdx.x;
  int m0 = mt * 64;
  #pragma unroll
  for (int rep = 0; rep < 16; ++rep) {
    int idx = rep * 256 + tid;
    int r = idx >> 6, c = idx & 63;
    t[r][c] = w[(h * 1024 + m0 + r) * 64 + c];
  }
  __syncthreads();
  #pragma unroll
  for (int rep = 0; rep < 16; ++rep) {
    int idx = rep * 256 + tid;
    int dr = idx >> 6, mc = idx & 63;
    const int row = which * 1024 + h * 64 + dr;
    o[row * 1024 + swzc(dr, m0 + mc)] = f2b(t[mc][dr]);
  }
}

// ---- w_o [1024 k][1024 m] f32 -> WoT[m][k] bf16, swizzled ----
__global__ void k_trans_wo(const float* __restrict__ wo, unsigned short* __restrict__ o) {
  __shared__ float t[64][65];
  int blk = blockIdx.x;            // 256
  int mt = blk & 15, kt = blk >> 4;
  int tid = threadIdx.x;
  int k0 = kt * 64, m0 = mt * 64;
  #pragma unroll
  for (int rep = 0; rep < 16; ++rep) {
    int idx = rep * 256 + tid;
    int r = idx >> 6, c = idx & 63;
    t[r][c] = wo[(k0 + r) * 1024 + m0 + c];
  }
  __syncthreads();
  #pragma unroll
  for (int rep = 0; rep < 16; ++rep) {
    int idx = rep * 256 + tid;
    int r = idx >> 6, c = idx & 63;
    o[(m0 + r) * 1024 + swzc(r, k0 + c)] = f2b(t[c][r]);
  }
}

// ---------------- 128x128 bf16 GEMM -> Q / Kc / Vc (fused N=3072) ----------------
// Stage-ahead-1 double-SET pipeline (compile-time sets), BK=64, 1 barrier/step.
#define QKV_STAGE(k0, SET)                                                    \
    GLDS16(aG0 + (k0),      As[SET] + lds0);                                  \
    GLDS16(aG1 + (k0),      As[SET] + lds1);                                  \
    GLDS16(aG0 + (k0) + 32, As[SET] + 4096 + lds0);                           \
    GLDS16(aG1 + (k0) + 32, As[SET] + 4096 + lds1);                           \
    GLDS16(bG0 + (k0),      Bs[SET] + lds0);                                  \
    GLDS16(bG1 + (k0),      Bs[SET] + lds1);                                  \
    GLDS16(bG0 + (k0) + 32, Bs[SET] + 4096 + lds0);                           \
    GLDS16(bG1 + (k0) + 32, Bs[SET] + 4096 + lds1);

#define GEMM_COMPUTE(SET)                                                     \
    _Pragma("unroll")                                                         \
    for (int p = 0; p < 2; ++p) {                                             \
      short8 a[4], b[4];                                                      \
      _Pragma("unroll")                                                       \
      for (int i = 0; i < 4; ++i)                                             \
        a[i] = *reinterpret_cast<const short8*>(As[SET] + p * 4096 + rowA + i * 512 + slot); \
      _Pragma("unroll")                                                       \
      for (int n = 0; n < 4; ++n)                                             \
        b[n] = *reinterpret_cast<const short8*>(Bs[SET] + p * 4096 + rowB + n * 512 + slot); \
      _Pragma("unroll")                                                       \
      for (int i = 0; i < 4; ++i)                                             \
        _Pragma("unroll")                                                     \
        for (int n = 0; n < 4; ++n)                                           \
          acc[i][n] = __builtin_amdgcn_mfma_f32_16x16x32_bf16(a[i], b[n], acc[i][n], 0, 0, 0); \
    }

#define VM0 asm volatile("s_waitcnt vmcnt(0)" ::: "memory")

__global__ __launch_bounds__(256) void k_gemm_qkv(const unsigned short* __restrict__ A,
                                                  const unsigned short* __restrict__ Bt,
                                                  unsigned short* __restrict__ Qb,
                                                  unsigned short* __restrict__ Kc,
                                                  unsigned short* __restrict__ Vc) {
  __shared__ unsigned short As[2][8192];   // [set][plane*4096 + row*32 + col]
  __shared__ unsigned short Bs[2][8192];
  const int bm = blockIdx.x, bn = blockIdx.y;
  const int tid = threadIdx.x;
  const int lane = tid & 63, wid = tid >> 6;
  const int wr = wid >> 1, wc = wid & 1;
  const int fr = lane & 15, fq = lane >> 4;

  f32x4 acc[4][4];
  #pragma unroll
  for (int i = 0; i < 4; ++i)
    #pragma unroll
    for (int n = 0; n < 4; ++n) acc[i][n] = f32x4{0.f, 0.f, 0.f, 0.f};

  const int arow = tid >> 2, acol = (tid & 3) * 8;
  const int lds0 = tid * 8, lds1 = (tid + 256) * 8;
  const unsigned short* aG0 = A + (bm * 128 + arow) * 1024 + acol;
  const unsigned short* aG1 = A + (bm * 128 + arow + 64) * 1024 + acol;
  const unsigned short* bG0 = Bt + (bn * 128 + arow) * 1024 + acol;
  const unsigned short* bG1 = Bt + (bn * 128 + arow + 64) * 1024 + acol;

  const int rowA = (wr * 64 + fr) * 32;
  const int rowB = (wc * 64 + fr) * 32;
  const int slot = ((fq ^ ((fr >> 1) & 3)) << 3);   // swizzled 16B slot

  QKV_STAGE(0, 0);
  for (int s2 = 0; s2 < 16; s2 += 2) {
    VM0;                      // step s2's stage (issued last half-iter) done
    __syncthreads();
    QKV_STAGE((s2 + 1) * 64, 1);
    GEMM_COMPUTE(0);
    VM0;                      // step s2+1's stage done (flew during compute)
    __syncthreads();
    if (s2 + 2 < 16) { QKV_STAGE((s2 + 2) * 64, 0); }
    GEMM_COMPUTE(1);
  }

  const float CS = 0.125f * 1.44269504088896340736f;
  const int colb = bn * 128 + wc * 64 + fr;
  const int rowb = bm * 128 + wr * 64 + fq * 4;
  #pragma unroll
  for (int n = 0; n < 4; ++n) {
    const int col = colb + n * 16;
    const int which = col >> 10, rc = col & 1023;
    const int h = rc >> 6, d = rc & 63;
    #pragma unroll
    for (int i = 0; i < 4; ++i) {
      const int row = rowb + i * 16;
      const int b_ = row >> 11, s = row & 2047;
      const int bh = b_ * 16 + h;
      if (which == 2) {
        const int c = s >> 5, kk = s & 31;
        const int r = d >> 1;
        const int sl = (((d & 1) * 4 + (kk >> 3)) ^ (r & 7));
        ushort4 v;
        v.x = f2b(acc[i][n][0]); v.y = f2b(acc[i][n][1]);
        v.z = f2b(acc[i][n][2]); v.w = f2b(acc[i][n][3]);
        *reinterpret_cast<ushort4*>(
            &Vc[((size_t)(bh * 64 + c)) * 2048 + r * 64 + sl * 8 + (kk & 7)]) = v;
      } else if (which == 1) {
        #pragma unroll
        for (int j = 0; j < 4; ++j) {
          const int ss = s + j;
          const int c = ss >> 5, r = ss & 31;
          const int dsw = (((d >> 3) ^ (r & 7)) << 3) | (d & 7);
          Kc[(((size_t)(bh * 64 + c)) * 32 + r) * 64 + dsw] = f2b(acc[i][n][j]);
        }
      } else {
        unsigned short* dst = Qb + ((size_t)bh * 2048 + s) * 64 + d;
        #pragma unroll
        for (int j = 0; j < 4; ++j) dst[j * 64] = f2b(acc[i][n][j] * CS);
      }
    }
  }
}

// ---------------- causal flash attention, LDS-staged K/V, swapped-QK^T 32x32 ----------------
// Triple-buffer stage-ahead-2, ONE barrier per chunk, counted vmcnt(2).

static __device__ __forceinline__ f32x16 mfma32(short8 a, short8 b, f32x16 c) {
  return __builtin_amdgcn_mfma_f32_32x32x16_bf16(a, b, c, 0, 0, 0);
}

template<bool MASKED>
static __device__ __forceinline__ void compute_chunk(
    const unsigned short* __restrict__ Kl, const unsigned short* __restrict__ Vl,
    int q, int hi,
    const short8& Qf0, const short8& Qf1, const short8& Qf2, const short8& Qf3,
    f32x16& accA, f32x16& accB, float& lsum) {
  const int qs = q & 7;
  const short8 kf0 = *reinterpret_cast<const short8*>(Kl + q * 64 + (((0 + hi) ^ qs) << 3));
  const short8 kf1 = *reinterpret_cast<const short8*>(Kl + q * 64 + (((2 + hi) ^ qs) << 3));
  const short8 kf2 = *reinterpret_cast<const short8*>(Kl + q * 64 + (((4 + hi) ^ qs) << 3));
  const short8 kf3 = *reinterpret_cast<const short8*>(Kl + q * 64 + (((6 + hi) ^ qs) << 3));
  const int vr = q >> 1, vs = (q & 1) * 4, vw = vr & 7;
  const short8 v00 = *reinterpret_cast<const short8*>(Vl + vr * 64 + (((vs + hi) ^ vw) << 3));
  const short8 v01 = *reinterpret_cast<const short8*>(Vl + vr * 64 + (((vs + 2 + hi) ^ vw) << 3));
  const short8 v10 = *reinterpret_cast<const short8*>(Vl + (vr + 16) * 64 + (((vs + hi) ^ vw) << 3));
  const short8 v11 = *reinterpret_cast<const short8*>(Vl + (vr + 16) * 64 + (((vs + 2 + hi) ^ vw) << 3));

  f32x16 s = {0.f,0.f,0.f,0.f,0.f,0.f,0.f,0.f,0.f,0.f,0.f,0.f,0.f,0.f,0.f,0.f};
  s = mfma32(kf0, Qf0, s);
  s = mfma32(kf1, Qf1, s);
  s = mfma32(kf2, Qf2, s);
  s = mfma32(kf3, Qf3, s);

  float p[16];
  #pragma unroll
  for (int r = 0; r < 16; ++r) {
    if (MASKED) {
      const int kr = (r & 3) + 8 * (r >> 2) + 4 * hi;
      p[r] = (kr <= q) ? __builtin_amdgcn_exp2f(s[r]) : 0.f;
    } else {
      p[r] = __builtin_amdgcn_exp2f(s[r]);
    }
  }
  float t0 = (p[0] + p[1]) + (p[2] + p[3]);
  float t1 = (p[4] + p[5]) + (p[6] + p[7]);
  float t2 = (p[8] + p[9]) + (p[10] + p[11]);
  float t3 = (p[12] + p[13]) + (p[14] + p[15]);
  lsum += (t0 + t1) + (t2 + t3);

  unsigned W[8], X[8];
  #pragma unroll
  for (int i = 0; i < 8; ++i)
    asm("v_cvt_pk_bf16_f32 %0, %1, %2" : "=v"(W[i]) : "v"(p[2 * i]), "v"(p[2 * i + 1]));
  #pragma unroll
  for (int i = 0; i < 8; ++i) X[i] = __shfl_xor(W[i], 32);

  union { unsigned u[4]; short8 v; } fa0, fa1;
  fa0.u[0] = hi ? X[2] : W[0];
  fa0.u[1] = hi ? X[3] : W[1];
  fa0.u[2] = hi ? W[2] : X[0];
  fa0.u[3] = hi ? W[3] : X[1];
  fa1.u[0] = hi ? X[6] : W[4];
  fa1.u[1] = hi ? X[7] : W[5];
  fa1.u[2] = hi ? W[6] : X[4];
  fa1.u[3] = hi ? W[7] : X[5];

  accA = mfma32(fa0.v, v00, accA);
  accA = mfma32(fa1.v, v01, accA);
  accB = mfma32(fa0.v, v10, accB);
  accB = mfma32(fa1.v, v11, accB);
}

// Zb is written slot-swizzled (it feeds k_gemm_out's A-staging).
static __device__ __forceinline__ void store_tile(unsigned short* __restrict__ Zb,
    int b_, int h, int q0, int q, int hi,
    const f32x16& a0, const f32x16& a1, float lsum) {
  const float lt = lsum + __shfl_xor(lsum, 32);
  const float rl = 1.f / lt;
  #pragma unroll
  for (int r = 0; r < 16; ++r) {
    const int qr = (r & 3) + 8 * (r >> 2) + 4 * hi;
    const float rlr = __shfl(rl, qr);
    const int row = b_ * 2048 + q0 + qr;
    const int sl = (((q >> 3) ^ ((qr >> 1) & 3)) << 3) + (q & 7);
    unsigned short* dst = Zb + (size_t)row * 1024 + h * 64;
    dst[sl]      = f2b(a0[r] * rlr);
    dst[32 + sl] = f2b(a1[r] * rlr);
  }
}

__global__ __launch_bounds__(256, 2) void k_attn(const unsigned short* __restrict__ Qb,
                                                 const unsigned short* __restrict__ Kc,
                                                 const unsigned short* __restrict__ Vc,
                                                 unsigned short* __restrict__ Zb) {
  __shared__ __align__(16) unsigned short Kbuf[3][2048];
  __shared__ __align__(16) unsigned short Vbuf[3][2048];
  const int tid = threadIdx.x;
  const int lane = tid & 63, w = tid >> 6;
  const int q = lane & 31, hi = lane >> 5;
  const int bid = blockIdx.x;                    // 0..511
  const int bh = (bid & 7) * 8 + ((bid >> 3) & 7);
  const int P1 = bid >> 6;                       // 0..7 -> pair (P1, 15-P1)
  const int b_ = bh >> 4, h = bh & 15;

  const unsigned short* Qbh = Qb + (size_t)bh * 2048 * 64;
  const unsigned short* Kch = Kc + (size_t)bh * 64 * 2048;
  const unsigned short* Vch = Vc + (size_t)bh * 64 * 2048;

  #pragma unroll 1
  for (int t = 0; t < 2; ++t) {
    const int P = t ? (15 - P1) : P1;
    const int q0 = 128 * P + 32 * w;
    const int cmax = 4 * P + w;
    const int C = 4 * P + 4;

    const unsigned short* Qp = Qbh + (size_t)(q0 + q) * 64 + hi * 8;
    const short8 Qf0 = *reinterpret_cast<const short8*>(Qp);
    const short8 Qf1 = *reinterpret_cast<const short8*>(Qp + 16);
    const short8 Qf2 = *reinterpret_cast<const short8*>(Qp + 32);
    const short8 Qf3 = *reinterpret_cast<const short8*>(Qp + 48);

    f32x16 a0 = {0.f,0.f,0.f,0.f,0.f,0.f,0.f,0.f,0.f,0.f,0.f,0.f,0.f,0.f,0.f,0.f};
    f32x16 a1 = a0;
    float l = 0.f;

    __syncthreads();   // previous t's readers done before restaging buf[0..1]
    GLDS16(Kch + tid * 8,        &Kbuf[0][tid * 8]);
    GLDS16(Vch + tid * 8,        &Vbuf[0][tid * 8]);
    GLDS16(Kch + 2048 + tid * 8, &Kbuf[1][tid * 8]);
    GLDS16(Vch + 2048 + tid * 8, &Vbuf[1][tid * 8]);

    int ci = 0, si = 2;
    for (int c = 0; c < C; ++c) {
      if (c == C - 1) { asm volatile("s_waitcnt vmcnt(0)" ::: "memory"); }
      else            { asm volatile("s_waitcnt vmcnt(2)" ::: "memory"); }
      __syncthreads();                           // chunk c visible block-wide
      if (c + 2 < C) {
        GLDS16(Kch + (size_t)(c + 2) * 2048 + tid * 8, &Kbuf[si][tid * 8]);
        GLDS16(Vch + (size_t)(c + 2) * 2048 + tid * 8, &Vbuf[si][tid * 8]);
      }
      if (c <= cmax) {
        if (c == cmax)
          compute_chunk<true>(Kbuf[ci], Vbuf[ci], q, hi, Qf0, Qf1, Qf2, Qf3, a0, a1, l);
        else
          compute_chunk<false>(Kbuf[ci], Vbuf[ci], q, hi, Qf0, Qf1, Qf2, Qf3, a0, a1, l);
      }
      ci = (ci + 1 == 3) ? 0 : ci + 1;
      si = (si + 1 == 3) ? 0 : si + 1;
    }
    store_tile(Zb, b_, h, q0, q, hi, a0, a1, l);
  }
}

// ---------------- 128x128 GEMM: out = Z @ Wo (BK=64, stage-ahead-1 pipeline) ----------------
__global__ __launch_bounds__(256) void k_gemm_out(const unsigned short* __restrict__ A,
                                                  const unsigned short* __restrict__ Bt,
                                                  float* __restrict__ Out) {
  __shared__ unsigned short As[2][8192];
  __shared__ unsigned short Bs[2][8192];
  const int bm = blockIdx.x, bn = blockIdx.y;
  const int tid = threadIdx.x;
  const int lane = tid & 63, wid = tid >> 6;
  const int wr = wid >> 1, wc = wid & 1;
  const int fr = lane & 15, fq = lane >> 4;

  f32x4 acc[4][4];
  #pragma unroll
  for (int i = 0; i < 4; ++i)
    #pragma unroll
    for (int n = 0; n < 4; ++n) acc[i][n] = f32x4{0.f, 0.f, 0.f, 0.f};

  const int arow = tid >> 2, acol = (tid & 3) * 8;
  const int lds0 = tid * 8, lds1 = (tid + 256) * 8;
  const unsigned short* aG0 = A + (bm * 128 + arow) * 1024 + acol;
  const unsigned short* aG1 = A + (bm * 128 + arow + 64) * 1024 + acol;
  const unsigned short* bG0 = Bt + (bn * 128 + arow) * 1024 + acol;
  const unsigned short* bG1 = Bt + (bn * 128 + arow + 64) * 1024 + acol;

  const int rowA = (wr * 64 + fr) * 32;
  const int rowB = (wc * 64 + fr) * 32;
  const int slot = ((fq ^ ((fr >> 1) & 3)) << 3);

  QKV_STAGE(0, 0);
  for (int s2 = 0; s2 < 16; s2 += 2) {
    VM0;
    __syncthreads();
    QKV_STAGE((s2 + 1) * 64, 1);
    GEMM_COMPUTE(0);
    VM0;
    __syncthreads();
    if (s2 + 2 < 16) { QKV_STAGE((s2 + 2) * 64, 0); }
    GEMM_COMPUTE(1);
  }

  const int colb = bn * 128 + wc * 64 + fr;
  const int rowb = bm * 128 + wr * 64 + fq * 4;
  #pragma unroll
  for (int n = 0; n < 4; ++n) {
    const int col = colb + n * 16;
    #pragma unroll
    for (int i = 0; i < 4; ++i) {
      const int row = rowb + i * 16;
      #pragma unroll
      for (int j = 0; j < 4; ++j) Out[(size_t)(row + j) * 1024 + col] = acc[i][n][j];
    }
  }
}

extern "C" void kernel_launch(void* const* d_in, const int* in_sizes, int n_in,
                              void* d_out, int out_size, void* d_ws, size_t ws_size,
                              hipStream_t stream) {
  const float* resid = (const float*)d_in[0];
  const float* w_q = (const float*)d_in[1];
  const float* w_k = (const float*)d_in[2];
  const float* w_v = (const float*)d_in[3];
  const float* w_o = (const float*)d_in[4];
  float* out = (float*)d_out;

  char* ws = (char*)d_ws;
  const size_t MB = 1u << 20;
  unsigned short* Xb = (unsigned short*)(ws);            // 16 MiB: resid bf16 swz; reused as Zb
  unsigned short* W3 = (unsigned short*)(ws + 16 * MB);  // 6 MiB : fused qkv B^T swz
  unsigned short* Wo = (unsigned short*)(ws + 22 * MB);  // 2 MiB : WoT swz
  unsigned short* Qb = (unsigned short*)(ws + 24 * MB);  // 16 MiB: Q [bh][s][d] (pre-scaled)
  unsigned short* Kc = (unsigned short*)(ws + 40 * MB);  // 16 MiB: K chunked+swizzled blobs
  unsigned short* Vc = (unsigned short*)(ws + 56 * MB);  // 16 MiB: V chunked+swizzled blobs
  unsigned short* Zb = Xb;                               // alias: Xb dead after k_gemm_qkv

  hipLaunchKernelGGL(k_cast, dim3(8192), dim3(256), 0, stream, resid, Xb, 8192 * 1024 / 4);
  hipLaunchKernelGGL(k_trans_qkv, dim3(768), dim3(256), 0, stream, w_q, w_k, w_v, W3);
  hipLaunchKernelGGL(k_trans_wo, dim3(256), dim3(256), 0, stream, w_o, Wo);
  hipLaunchKernelGGL(k_gemm_qkv, dim3(64, 24), dim3(256), 0, stream, Xb, W3, Qb, Kc, Vc);
  hipLaunchKernelGGL(k_attn, dim3(512), dim3(256), 0, stream, Qb, Kc, Vc, Zb);
  hipLaunchKernelGGL(k_gemm_out, dim3(64, 8), dim3(256), 0, stream, Zb, Wo, out);
}

// Round 16
// 164.973 us; speedup vs baseline: 1.1966x; 1.0046x over previous
//
#include <hip/hip_runtime.h>

// Attention_29583734734990 : resid[4,2048,1024] f32, w_q/k/v[16,1024,64], w_o[16,64,1024]
// out[4,2048,1024] f32.  bf16 MFMA pipeline (threshold is bf16-floor 3.14e-2).
//
// GEMM input arrays (Xb, W3, Wo, Zb) are stored SLOT-SWIZZLED: within each
// 32-element k-chunk, 16B slot index ^= ((row>>1)&3).  global_load_lds stages
// chunks linearly; LDS readers XOR the same involution (rule-21 both-sides).

typedef __attribute__((ext_vector_type(8))) short short8;
typedef __attribute__((ext_vector_type(4))) float f32x4;
typedef __attribute__((ext_vector_type(16))) float f32x16;

#define GLDS16(g, l) __builtin_amdgcn_global_load_lds(                        \
    (const __attribute__((address_space(1))) unsigned int*)(g),               \
    (__attribute__((address_space(3))) unsigned int*)(l), 16, 0, 0)

#define VM0 asm volatile("s_waitcnt vmcnt(0)" ::: "memory")

static __device__ __forceinline__ unsigned short f2b(float f) {
  union { float f; unsigned u; } c; c.f = f;
  unsigned r = c.u + 0x7fffu + ((c.u >> 16) & 1u);
  return (unsigned short)(r >> 16);
}

// slot swizzle: element (row, c) of a [rows][1024] k-major array
static __device__ __forceinline__ int swzc(int row, int c) {
  return (c & ~31) | ((((c >> 3) & 3) ^ ((row >> 1) & 3)) << 3) | (c & 7);
}

// ---------------- cast resid f32 -> bf16 [8192][1024], slot-swizzled ----------------
__global__ void k_cast(const float* __restrict__ x, unsigned short* __restrict__ o, int n4) {
  int i = blockIdx.x * blockDim.x + threadIdx.x;
  if (i >= n4) return;
  float4 v = reinterpret_cast<const float4*>(x)[i];
  ushort4 u;
  u.x = f2b(v.x); u.y = f2b(v.y); u.z = f2b(v.z); u.w = f2b(v.w);
  const int flat = i * 4;
  const int row = flat >> 10, c = flat & 1023;
  *reinterpret_cast<ushort4*>(&o[row * 1024 + swzc(row, c)]) = u;
}

// ---- w_q/w_k/w_v [16][1024][64] f32 -> W3t[(which*1024+h*64+d)][1024 m] bf16, swizzled ----
__global__ void k_trans_qkv(const float* __restrict__ wq, const float* __restrict__ wk,
                            const float* __restrict__ wv, unsigned short* __restrict__ o) {
  __shared__ float t[64][65];
  int blk = blockIdx.x;            // 3*16*16
  int mt = blk & 15;
  int h = (blk >> 4) & 15;
  int which = blk >> 8;
  const float* w = which == 0 ? wq : (which == 1 ? wk : wv);
  int tid = threadIdx.x;
  int m0 = mt * 64;
  #pragma unroll
  for (int rep = 0; rep < 16; ++rep) {
    int idx = rep * 256 + tid;
    int r = idx >> 6, c = idx & 63;
    t[r][c] = w[(h * 1024 + m0 + r) * 64 + c];
  }
  __syncthreads();
  #pragma unroll
  for (int rep = 0; rep < 16; ++rep) {
    int idx = rep * 256 + tid;
    int dr = idx >> 6, mc = idx & 63;
    const int row = which * 1024 + h * 64 + dr;
    o[row * 1024 + swzc(dr, m0 + mc)] = f2b(t[mc][dr]);
  }
}

// ---- w_o [1024 k][1024 m] f32 -> WoT[m][k] bf16, swizzled ----
__global__ void k_trans_wo(const float* __restrict__ wo, unsigned short* __restrict__ o) {
  __shared__ float t[64][65];
  int blk = blockIdx.x;            // 256
  int mt = blk & 15, kt = blk >> 4;
  int tid = threadIdx.x;
  int k0 = kt * 64, m0 = mt * 64;
  #pragma unroll
  for (int rep = 0; rep < 16; ++rep) {
    int idx = rep * 256 + tid;
    int r = idx >> 6, c = idx & 63;
    t[r][c] = wo[(k0 + r) * 1024 + m0 + c];
  }
  __syncthreads();
  #pragma unroll
  for (int rep = 0; rep < 16; ++rep) {
    int idx = rep * 256 + tid;
    int r = idx >> 6, c = idx & 63;
    o[(m0 + r) * 1024 + swzc(r, k0 + c)] = f2b(t[c][r]);
  }
}

// ---------------- 128x128 bf16 GEMM -> Q / Kc / Vc (fused N=3072) ----------------
// r14 schedule: stage -> vmcnt(0) -> barrier -> compute, BK=64 via two 32-col planes.
__global__ __launch_bounds__(256) void k_gemm_qkv(const unsigned short* __restrict__ A,
                                                  const unsigned short* __restrict__ Bt,
                                                  unsigned short* __restrict__ Qb,
                                                  unsigned short* __restrict__ Kc,
                                                  unsigned short* __restrict__ Vc) {
  __shared__ unsigned short As[2][128 * 32];
  __shared__ unsigned short Bs[2][128 * 32];
  const int bm = blockIdx.x, bn = blockIdx.y;
  const int tid = threadIdx.x;
  const int lane = tid & 63, wid = tid >> 6;
  const int wr = wid >> 1, wc = wid & 1;
  const int fr = lane & 15, fq = lane >> 4;

  f32x4 acc[4][4];
  #pragma unroll
  for (int i = 0; i < 4; ++i)
    #pragma unroll
    for (int n = 0; n < 4; ++n) acc[i][n] = f32x4{0.f, 0.f, 0.f, 0.f};

  const int arow = tid >> 2, acol = (tid & 3) * 8;
  const int lds0 = tid * 8, lds1 = (tid + 256) * 8;
  const unsigned short* aG0 = A + (bm * 128 + arow) * 1024 + acol;
  const unsigned short* aG1 = A + (bm * 128 + arow + 64) * 1024 + acol;
  const unsigned short* bG0 = Bt + (bn * 128 + arow) * 1024 + acol;
  const unsigned short* bG1 = Bt + (bn * 128 + arow + 64) * 1024 + acol;

  const int rowA = (wr * 64 + fr) * 32;
  const int rowB = (wc * 64 + fr) * 32;
  const int slot = ((fq ^ ((fr >> 1) & 3)) << 3);   // swizzled 16B slot

  for (int k0 = 0; k0 < 1024; k0 += 64) {
    __syncthreads();
    GLDS16(aG0 + k0,      As[0] + lds0);
    GLDS16(aG1 + k0,      As[0] + lds1);
    GLDS16(aG0 + k0 + 32, As[1] + lds0);
    GLDS16(aG1 + k0 + 32, As[1] + lds1);
    GLDS16(bG0 + k0,      Bs[0] + lds0);
    GLDS16(bG1 + k0,      Bs[0] + lds1);
    GLDS16(bG0 + k0 + 32, Bs[1] + lds0);
    GLDS16(bG1 + k0 + 32, Bs[1] + lds1);
    VM0;
    __syncthreads();
    #pragma unroll
    for (int p = 0; p < 2; ++p) {
      short8 a[4], b[4];
      #pragma unroll
      for (int i = 0; i < 4; ++i)
        a[i] = *reinterpret_cast<const short8*>(As[p] + rowA + i * 512 + slot);
      #pragma unroll
      for (int n = 0; n < 4; ++n)
        b[n] = *reinterpret_cast<const short8*>(Bs[p] + rowB + n * 512 + slot);
      #pragma unroll
      for (int i = 0; i < 4; ++i)
        #pragma unroll
        for (int n = 0; n < 4; ++n)
          acc[i][n] = __builtin_amdgcn_mfma_f32_16x16x32_bf16(a[i], b[n], acc[i][n], 0, 0, 0);
    }
  }

  const float CS = 0.125f * 1.44269504088896340736f;
  const int colb = bn * 128 + wc * 64 + fr;
  const int rowb = bm * 128 + wr * 64 + fq * 4;
  #pragma unroll
  for (int n = 0; n < 4; ++n) {
    const int col = colb + n * 16;
    const int which = col >> 10, rc = col & 1023;
    const int h = rc >> 6, d = rc & 63;
    #pragma unroll
    for (int i = 0; i < 4; ++i) {
      const int row = rowb + i * 16;
      const int b_ = row >> 11, s = row & 2047;
      const int bh = b_ * 16 + h;
      if (which == 2) {
        const int c = s >> 5, kk = s & 31;
        const int r = d >> 1;
        const int sl = (((d & 1) * 4 + (kk >> 3)) ^ (r & 7));
        ushort4 v;
        v.x = f2b(acc[i][n][0]); v.y = f2b(acc[i][n][1]);
        v.z = f2b(acc[i][n][2]); v.w = f2b(acc[i][n][3]);
        *reinterpret_cast<ushort4*>(
            &Vc[((size_t)(bh * 64 + c)) * 2048 + r * 64 + sl * 8 + (kk & 7)]) = v;
      } else if (which == 1) {
        #pragma unroll
        for (int j = 0; j < 4; ++j) {
          const int ss = s + j;
          const int c = ss >> 5, r = ss & 31;
          const int dsw = (((d >> 3) ^ (r & 7)) << 3) | (d & 7);
          Kc[(((size_t)(bh * 64 + c)) * 32 + r) * 64 + dsw] = f2b(acc[i][n][j]);
        }
      } else {
        unsigned short* dst = Qb + ((size_t)bh * 2048 + s) * 64 + d;
        #pragma unroll
        for (int j = 0; j < 4; ++j) dst[j * 64] = f2b(acc[i][n][j] * CS);
      }
    }
  }
}

// ---------------- causal flash attention: FUSED-PAIR single pass ----------------
// Block owns tile pair (P1, 15-P1) of one bh; each staged chunk feeds BOTH tiles.
// Triple-buffer stage-ahead-2, one convergent barrier/chunk, counted vmcnt(2).
// bid decode pairs complementary P1 on co-resident blocks (uniform CU load).

static __device__ __forceinline__ f32x16 mfma32(short8 a, short8 b, f32x16 c) {
  return __builtin_amdgcn_mfma_f32_32x32x16_bf16(a, b, c, 0, 0, 0);
}

template<bool MASKED>
static __device__ __forceinline__ void compute_chunk(
    const unsigned short* __restrict__ Kl, const unsigned short* __restrict__ Vl,
    int q, int hi,
    const short8& Qf0, const short8& Qf1, const short8& Qf2, const short8& Qf3,
    f32x16& accA, f32x16& accB, float& lsum) {
  const int qs = q & 7;
  const short8 kf0 = *reinterpret_cast<const short8*>(Kl + q * 64 + (((0 + hi) ^ qs) << 3));
  const short8 kf1 = *reinterpret_cast<const short8*>(Kl + q * 64 + (((2 + hi) ^ qs) << 3));
  const short8 kf2 = *reinterpret_cast<const short8*>(Kl + q * 64 + (((4 + hi) ^ qs) << 3));
  const short8 kf3 = *reinterpret_cast<const short8*>(Kl + q * 64 + (((6 + hi) ^ qs) << 3));
  const int vr = q >> 1, vs = (q & 1) * 4, vw = vr & 7;
  const short8 v00 = *reinterpret_cast<const short8*>(Vl + vr * 64 + (((vs + hi) ^ vw) << 3));
  const short8 v01 = *reinterpret_cast<const short8*>(Vl + vr * 64 + (((vs + 2 + hi) ^ vw) << 3));
  const short8 v10 = *reinterpret_cast<const short8*>(Vl + (vr + 16) * 64 + (((vs + hi) ^ vw) << 3));
  const short8 v11 = *reinterpret_cast<const short8*>(Vl + (vr + 16) * 64 + (((vs + 2 + hi) ^ vw) << 3));

  f32x16 s = {0.f,0.f,0.f,0.f,0.f,0.f,0.f,0.f,0.f,0.f,0.f,0.f,0.f,0.f,0.f,0.f};
  s = mfma32(kf0, Qf0, s);
  s = mfma32(kf1, Qf1, s);
  s = mfma32(kf2, Qf2, s);
  s = mfma32(kf3, Qf3, s);

  float p[16];
  #pragma unroll
  for (int r = 0; r < 16; ++r) {
    if (MASKED) {
      const int kr = (r & 3) + 8 * (r >> 2) + 4 * hi;
      p[r] = (kr <= q) ? __builtin_amdgcn_exp2f(s[r]) : 0.f;
    } else {
      p[r] = __builtin_amdgcn_exp2f(s[r]);
    }
  }
  float t0 = (p[0] + p[1]) + (p[2] + p[3]);
  float t1 = (p[4] + p[5]) + (p[6] + p[7]);
  float t2 = (p[8] + p[9]) + (p[10] + p[11]);
  float t3 = (p[12] + p[13]) + (p[14] + p[15]);
  lsum += (t0 + t1) + (t2 + t3);

  unsigned W[8], X[8];
  #pragma unroll
  for (int i = 0; i < 8; ++i)
    asm("v_cvt_pk_bf16_f32 %0, %1, %2" : "=v"(W[i]) : "v"(p[2 * i]), "v"(p[2 * i + 1]));
  #pragma unroll
  for (int i = 0; i < 8; ++i) X[i] = __shfl_xor(W[i], 32);

  union { unsigned u[4]; short8 v; } fa0, fa1;
  fa0.u[0] = hi ? X[2] : W[0];
  fa0.u[1] = hi ? X[3] : W[1];
  fa0.u[2] = hi ? W[2] : X[0];
  fa0.u[3] = hi ? W[3] : X[1];
  fa1.u[0] = hi ? X[6] : W[4];
  fa1.u[1] = hi ? X[7] : W[5];
  fa1.u[2] = hi ? W[6] : X[4];
  fa1.u[3] = hi ? W[7] : X[5];

  accA = mfma32(fa0.v, v00, accA);
  accA = mfma32(fa1.v, v01, accA);
  accB = mfma32(fa0.v, v10, accB);
  accB = mfma32(fa1.v, v11, accB);
}

// Zb is written slot-swizzled (it feeds k_gemm_out's A-staging).
static __device__ __forceinline__ void store_tile(unsigned short* __restrict__ Zb,
    int b_, int h, int q0, int q, int hi,
    const f32x16& a0, const f32x16& a1, float lsum) {
  const float lt = lsum + __shfl_xor(lsum, 32);
  const float rl = 1.f / lt;
  #pragma unroll
  for (int r = 0; r < 16; ++r) {
    const int qr = (r & 3) + 8 * (r >> 2) + 4 * hi;
    const float rlr = __shfl(rl, qr);
    const int row = b_ * 2048 + q0 + qr;
    const int sl = (((q >> 3) ^ ((qr >> 1) & 3)) << 3) + (q & 7);
    unsigned short* dst = Zb + (size_t)row * 1024 + h * 64;
    dst[sl]      = f2b(a0[r] * rlr);
    dst[32 + sl] = f2b(a1[r] * rlr);
  }
}

__global__ __launch_bounds__(256, 2) void k_attn(const unsigned short* __restrict__ Qb,
                                                 const unsigned short* __restrict__ Kc,
                                                 const unsigned short* __restrict__ Vc,
                                                 unsigned short* __restrict__ Zb) {
  __shared__ __align__(16) unsigned short Kbuf[3][2048];
  __shared__ __align__(16) unsigned short Vbuf[3][2048];
  const int tid = threadIdx.x;
  const int lane = tid & 63, w = tid >> 6;
  const int q = lane & 31, hi = lane >> 5;
  // decode: XCD-pinned bh; co-resident block pairs get complementary P1 and same bh.
  const int bid = blockIdx.x;                  // 0..511
  const int g = bid & 7;                       // XCD
  const int sdec = bid >> 3;                   // 0..63
  const int par = sdec & 1;
  const int jj = sdec >> 1;                    // 0..31
  const int bh = g * 8 + (jj & 7);
  const int x = jj >> 3;                       // 0..3
  const int P1 = par ? (7 - x) : x;            // 0..7
  const int q0A = 128 * P1 + 32 * w;
  const int q0B = 128 * (15 - P1) + 32 * w;
  const int cmaxA = 4 * P1 + w;
  const int cmaxB = 4 * (15 - P1) + w;
  const int C = 4 * (15 - P1) + 4;             // chunks staged (tile B's need)
  const int b_ = bh >> 4, h = bh & 15;

  const unsigned short* Qbh = Qb + (size_t)bh * 2048 * 64;
  const unsigned short* Kch = Kc + (size_t)bh * 64 * 2048;
  const unsigned short* Vch = Vc + (size_t)bh * 64 * 2048;

  const unsigned short* QpA = Qbh + (size_t)(q0A + q) * 64 + hi * 8;
  const short8 QA0 = *reinterpret_cast<const short8*>(QpA);
  const short8 QA1 = *reinterpret_cast<const short8*>(QpA + 16);
  const short8 QA2 = *reinterpret_cast<const short8*>(QpA + 32);
  const short8 QA3 = *reinterpret_cast<const short8*>(QpA + 48);
  const unsigned short* QpB = Qbh + (size_t)(q0B + q) * 64 + hi * 8;
  const short8 QB0 = *reinterpret_cast<const short8*>(QpB);
  const short8 QB1 = *reinterpret_cast<const short8*>(QpB + 16);
  const short8 QB2 = *reinterpret_cast<const short8*>(QpB + 32);
  const short8 QB3 = *reinterpret_cast<const short8*>(QpB + 48);

  const f32x16 zero = {0.f,0.f,0.f,0.f,0.f,0.f,0.f,0.f,0.f,0.f,0.f,0.f,0.f,0.f,0.f,0.f};
  f32x16 aA0 = zero, aA1 = zero, aB0 = zero, aB1 = zero;
  float lA = 0.f, lB = 0.f;

  GLDS16(Kch + tid * 8,        &Kbuf[0][tid * 8]);
  GLDS16(Vch + tid * 8,        &Vbuf[0][tid * 8]);
  GLDS16(Kch + 2048 + tid * 8, &Kbuf[1][tid * 8]);
  GLDS16(Vch + 2048 + tid * 8, &Vbuf[1][tid * 8]);

  int ci = 0, si = 2;
  for (int c = 0; c < C; ++c) {
    if (c == C - 1) { VM0; }
    else            { asm volatile("s_waitcnt vmcnt(2)" ::: "memory"); }
    __syncthreads();                           // chunk c visible; prior reads done
    if (c + 2 < C) {
      GLDS16(Kch + (size_t)(c + 2) * 2048 + tid * 8, &Kbuf[si][tid * 8]);
      GLDS16(Vch + (size_t)(c + 2) * 2048 + tid * 8, &Vbuf[si][tid * 8]);
    }
    if (c <= cmaxA) {
      if (c == cmaxA)
        compute_chunk<true >(Kbuf[ci], Vbuf[ci], q, hi, QA0, QA1, QA2, QA3, aA0, aA1, lA);
      else
        compute_chunk<false>(Kbuf[ci], Vbuf[ci], q, hi, QA0, QA1, QA2, QA3, aA0, aA1, lA);
    }
    if (c <= cmaxB) {
      if (c == cmaxB)
        compute_chunk<true >(Kbuf[ci], Vbuf[ci], q, hi, QB0, QB1, QB2, QB3, aB0, aB1, lB);
      else
        compute_chunk<false>(Kbuf[ci], Vbuf[ci], q, hi, QB0, QB1, QB2, QB3, aB0, aB1, lB);
    }
    ci = (ci + 1 == 3) ? 0 : ci + 1;
    si = (si + 1 == 3) ? 0 : si + 1;
  }
  store_tile(Zb, b_, h, q0A, q, hi, aA0, aA1, lA);
  store_tile(Zb, b_, h, q0B, q, hi, aB0, aB1, lB);
}

// ---------------- 128x128 GEMM: out = Z @ Wo (BK=64 two-plane, r14 schedule) ----------------
__global__ __launch_bounds__(256) void k_gemm_out(const unsigned short* __restrict__ A,
                                                  const unsigned short* __restrict__ Bt,
                                                  float* __restrict__ Out) {
  __shared__ unsigned short As[2][128 * 32];
  __shared__ unsigned short Bs[2][128 * 32];
  const int bm = blockIdx.x, bn = blockIdx.y;
  const int tid = threadIdx.x;
  const int lane = tid & 63, wid = tid >> 6;
  const int wr = wid >> 1, wc = wid & 1;
  const int fr = lane & 15, fq = lane >> 4;

  f32x4 acc[4][4];
  #pragma unroll
  for (int i = 0; i < 4; ++i)
    #pragma unroll
    for (int n = 0; n < 4; ++n) acc[i][n] = f32x4{0.f, 0.f, 0.f, 0.f};

  const int arow = tid >> 2, acol = (tid & 3) * 8;
  const int lds0 = tid * 8, lds1 = (tid + 256) * 8;
  const unsigned short* aG0 = A + (bm * 128 + arow) * 1024 + acol;
  const unsigned short* aG1 = A + (bm * 128 + arow + 64) * 1024 + acol;
  const unsigned short* bG0 = Bt + (bn * 128 + arow) * 1024 + acol;
  const unsigned short* bG1 = Bt + (bn * 128 + arow + 64) * 1024 + acol;

  const int rowA = (wr * 64 + fr) * 32;
  const int rowB = (wc * 64 + fr) * 32;
  const int slot = ((fq ^ ((fr >> 1) & 3)) << 3);

  for (int k0 = 0; k0 < 1024; k0 += 64) {
    __syncthreads();
    GLDS16(aG0 + k0,      As[0] + lds0);
    GLDS16(aG1 + k0,      As[0] + lds1);
    GLDS16(aG0 + k0 + 32, As[1] + lds0);
    GLDS16(aG1 + k0 + 32, As[1] + lds1);
    GLDS16(bG0 + k0,      Bs[0] + lds0);
    GLDS16(bG1 + k0,      Bs[0] + lds1);
    GLDS16(bG0 + k0 + 32, Bs[1] + lds0);
    GLDS16(bG1 + k0 + 32, Bs[1] + lds1);
    VM0;
    __syncthreads();
    #pragma unroll
    for (int p = 0; p < 2; ++p) {
      short8 a[4], b[4];
      #pragma unroll
      for (int i = 0; i < 4; ++i)
        a[i] = *reinterpret_cast<const short8*>(As[p] + rowA + i * 512 + slot);
      #pragma unroll
      for (int n = 0; n < 4; ++n)
        b[n] = *reinterpret_cast<const short8*>(Bs[p] + rowB + n * 512 + slot);
      #pragma unroll
      for (int i = 0; i < 4; ++i)
        #pragma unroll
        for (int n = 0; n < 4; ++n)
          acc[i][n] = __builtin_amdgcn_mfma_f32_16x16x32_bf16(a[i], b[n], acc[i][n], 0, 0, 0);
    }
  }

  const int colb = bn * 128 + wc * 64 + fr;
  const int rowb = bm * 128 + wr * 64 + fq * 4;
  #pragma unroll
  for (int n = 0; n < 4; ++n) {
    const int col = colb + n * 16;
    #pragma unroll
    for (int i = 0; i < 4; ++i) {
      const int row = rowb + i * 16;
      #pragma unroll
      for (int j = 0; j < 4; ++j) Out[(size_t)(row + j) * 1024 + col] = acc[i][n][j];
    }
  }
}

extern "C" void kernel_launch(void* const* d_in, const int* in_sizes, int n_in,
                              void* d_out, int out_size, void* d_ws, size_t ws_size,
                              hipStream_t stream) {
  const float* resid = (const float*)d_in[0];
  const float* w_q = (const float*)d_in[1];
  const float* w_k = (const float*)d_in[2];
  const float* w_v = (const float*)d_in[3];
  const float* w_o = (const float*)d_in[4];
  float* out = (float*)d_out;

  char* ws = (char*)d_ws;
  const size_t MB = 1u << 20;
  unsigned short* Xb = (unsigned short*)(ws);            // 16 MiB: resid bf16 swz; reused as Zb
  unsigned short* W3 = (unsigned short*)(ws + 16 * MB);  // 6 MiB : fused qkv B^T swz
  unsigned short* Wo = (unsigned short*)(ws + 22 * MB);  // 2 MiB : WoT swz
  unsigned short* Qb = (unsigned short*)(ws + 24 * MB);  // 16 MiB: Q [bh][s][d] (pre-scaled)
  unsigned short* Kc = (unsigned short*)(ws + 40 * MB);  // 16 MiB: K chunked+swizzled blobs
  unsigned short* Vc = (unsigned short*)(ws + 56 * MB);  // 16 MiB: V chunked+swizzled blobs
  unsigned short* Zb = Xb;                               // alias: Xb dead after k_gemm_qkv

  hipLaunchKernelGGL(k_cast, dim3(8192), dim3(256), 0, stream, resid, Xb, 8192 * 1024 / 4);
  hipLaunchKernelGGL(k_trans_qkv, dim3(768), dim3(256), 0, stream, w_q, w_k, w_v, W3);
  hipLaunchKernelGGL(k_trans_wo, dim3(256), dim3(256), 0, stream, w_o, Wo);
  hipLaunchKernelGGL(k_gemm_qkv, dim3(64, 24), dim3(256), 0, stream, Xb, W3, Qb, Kc, Vc);
  hipLaunchKernelGGL(k_attn, dim3(512), dim3(256), 0, stream, Qb, Kc, Vc, Zb);
  hipLaunchKernelGGL(k_gemm_out, dim3(64, 8), dim3(256), 0, stream, Zb, Wo, out);
}

// Round 17
// 160.812 us; speedup vs baseline: 1.2275x; 1.0259x over previous
//
#include <hip/hip_runtime.h>

// Attention_29583734734990 : resid[4,2048,1024] f32, w_q/k/v[16,1024,64], w_o[16,64,1024]
// out[4,2048,1024] f32.  bf16 MFMA pipeline (threshold is bf16-floor 3.14e-2).
//
// GEMM input arrays (Xb, W3, Wo, Zb) are stored SLOT-SWIZZLED: within each
// 32-element k-chunk, 16B slot index ^= ((row>>1)&3).  global_load_lds stages
// chunks linearly; LDS readers XOR the same involution (rule-21 both-sides).

typedef __attribute__((ext_vector_type(8))) short short8;
typedef __attribute__((ext_vector_type(4))) float f32x4;
typedef __attribute__((ext_vector_type(16))) float f32x16;

#define GLDS16(g, l) __builtin_amdgcn_global_load_lds(                        \
    (const __attribute__((address_space(1))) unsigned int*)(g),               \
    (__attribute__((address_space(3))) unsigned int*)(l), 16, 0, 0)

#define VM0 asm volatile("s_waitcnt vmcnt(0)" ::: "memory")

static __device__ __forceinline__ unsigned short f2b(float f) {
  union { float f; unsigned u; } c; c.f = f;
  unsigned r = c.u + 0x7fffu + ((c.u >> 16) & 1u);
  return (unsigned short)(r >> 16);
}

// slot swizzle: element (row, c) of a [rows][1024] k-major array
static __device__ __forceinline__ int swzc(int row, int c) {
  return (c & ~31) | ((((c >> 3) & 3) ^ ((row >> 1) & 3)) << 3) | (c & 7);
}

// ---------------- cast resid f32 -> bf16 [8192][1024], slot-swizzled ----------------
__global__ void k_cast(const float* __restrict__ x, unsigned short* __restrict__ o, int n4) {
  int i = blockIdx.x * blockDim.x + threadIdx.x;
  if (i >= n4) return;
  float4 v = reinterpret_cast<const float4*>(x)[i];
  ushort4 u;
  u.x = f2b(v.x); u.y = f2b(v.y); u.z = f2b(v.z); u.w = f2b(v.w);
  const int flat = i * 4;
  const int row = flat >> 10, c = flat & 1023;
  *reinterpret_cast<ushort4*>(&o[row * 1024 + swzc(row, c)]) = u;
}

// ---- w_q/w_k/w_v [16][1024][64] f32 -> W3t[(which*1024+h*64+d)][1024 m] bf16, swizzled ----
__global__ void k_trans_qkv(const float* __restrict__ wq, const float* __restrict__ wk,
                            const float* __restrict__ wv, unsigned short* __restrict__ o) {
  __shared__ float t[64][65];
  int blk = blockIdx.x;            // 3*16*16
  int mt = blk & 15;
  int h = (blk >> 4) & 15;
  int which = blk >> 8;
  const float* w = which == 0 ? wq : (which == 1 ? wk : wv);
  int tid = threadIdx.x;
  int m0 = mt * 64;
  #pragma unroll
  for (int rep = 0; rep < 16; ++rep) {
    int idx = rep * 256 + tid;
    int r = idx >> 6, c = idx & 63;
    t[r][c] = w[(h * 1024 + m0 + r) * 64 + c];
  }
  __syncthreads();
  #pragma unroll
  for (int rep = 0; rep < 16; ++rep) {
    int idx = rep * 256 + tid;
    int dr = idx >> 6, mc = idx & 63;
    const int row = which * 1024 + h * 64 + dr;
    o[row * 1024 + swzc(dr, m0 + mc)] = f2b(t[mc][dr]);
  }
}

// ---- w_o [1024 k][1024 m] f32 -> WoT[m][k] bf16, swizzled ----
__global__ void k_trans_wo(const float* __restrict__ wo, unsigned short* __restrict__ o) {
  __shared__ float t[64][65];
  int blk = blockIdx.x;            // 256
  int mt = blk & 15, kt = blk >> 4;
  int tid = threadIdx.x;
  int k0 = kt * 64, m0 = mt * 64;
  #pragma unroll
  for (int rep = 0; rep < 16; ++rep) {
    int idx = rep * 256 + tid;
    int r = idx >> 6, c = idx & 63;
    t[r][c] = wo[(k0 + r) * 1024 + m0 + c];
  }
  __syncthreads();
  #pragma unroll
  for (int rep = 0; rep < 16; ++rep) {
    int idx = rep * 256 + tid;
    int r = idx >> 6, c = idx & 63;
    o[(m0 + r) * 1024 + swzc(r, k0 + c)] = f2b(t[c][r]);
  }
}

// ---------------- 128x128 bf16 GEMM -> Q / Kc / Vc (fused N=3072) ----------------
// r14 schedule: stage -> vmcnt(0) -> barrier -> compute, BK=64 via two 32-col planes.
__global__ __launch_bounds__(256) void k_gemm_qkv(const unsigned short* __restrict__ A,
                                                  const unsigned short* __restrict__ Bt,
                                                  unsigned short* __restrict__ Qb,
                                                  unsigned short* __restrict__ Kc,
                                                  unsigned short* __restrict__ Vc) {
  __shared__ unsigned short As[2][128 * 32];
  __shared__ unsigned short Bs[2][128 * 32];
  const int bm = blockIdx.x, bn = blockIdx.y;
  const int tid = threadIdx.x;
  const int lane = tid & 63, wid = tid >> 6;
  const int wr = wid >> 1, wc = wid & 1;
  const int fr = lane & 15, fq = lane >> 4;

  f32x4 acc[4][4];
  #pragma unroll
  for (int i = 0; i < 4; ++i)
    #pragma unroll
    for (int n = 0; n < 4; ++n) acc[i][n] = f32x4{0.f, 0.f, 0.f, 0.f};

  const int arow = tid >> 2, acol = (tid & 3) * 8;
  const int lds0 = tid * 8, lds1 = (tid + 256) * 8;
  const unsigned short* aG0 = A + (bm * 128 + arow) * 1024 + acol;
  const unsigned short* aG1 = A + (bm * 128 + arow + 64) * 1024 + acol;
  const unsigned short* bG0 = Bt + (bn * 128 + arow) * 1024 + acol;
  const unsigned short* bG1 = Bt + (bn * 128 + arow + 64) * 1024 + acol;

  const int rowA = (wr * 64 + fr) * 32;
  const int rowB = (wc * 64 + fr) * 32;
  const int slot = ((fq ^ ((fr >> 1) & 3)) << 3);   // swizzled 16B slot

  for (int k0 = 0; k0 < 1024; k0 += 64) {
    __syncthreads();
    GLDS16(aG0 + k0,      As[0] + lds0);
    GLDS16(aG1 + k0,      As[0] + lds1);
    GLDS16(aG0 + k0 + 32, As[1] + lds0);
    GLDS16(aG1 + k0 + 32, As[1] + lds1);
    GLDS16(bG0 + k0,      Bs[0] + lds0);
    GLDS16(bG1 + k0,      Bs[0] + lds1);
    GLDS16(bG0 + k0 + 32, Bs[1] + lds0);
    GLDS16(bG1 + k0 + 32, Bs[1] + lds1);
    VM0;
    __syncthreads();
    #pragma unroll
    for (int p = 0; p < 2; ++p) {
      short8 a[4], b[4];
      #pragma unroll
      for (int i = 0; i < 4; ++i)
        a[i] = *reinterpret_cast<const short8*>(As[p] + rowA + i * 512 + slot);
      #pragma unroll
      for (int n = 0; n < 4; ++n)
        b[n] = *reinterpret_cast<const short8*>(Bs[p] + rowB + n * 512 + slot);
      #pragma unroll
      for (int i = 0; i < 4; ++i)
        #pragma unroll
        for (int n = 0; n < 4; ++n)
          acc[i][n] = __builtin_amdgcn_mfma_f32_16x16x32_bf16(a[i], b[n], acc[i][n], 0, 0, 0);
    }
  }

  const float CS = 0.125f * 1.44269504088896340736f;
  const int colb = bn * 128 + wc * 64 + fr;
  const int rowb = bm * 128 + wr * 64 + fq * 4;
  #pragma unroll
  for (int n = 0; n < 4; ++n) {
    const int col = colb + n * 16;
    const int which = col >> 10, rc = col & 1023;
    const int h = rc >> 6, d = rc & 63;
    #pragma unroll
    for (int i = 0; i < 4; ++i) {
      const int row = rowb + i * 16;
      const int b_ = row >> 11, s = row & 2047;
      const int bh = b_ * 16 + h;
      if (which == 2) {
        const int c = s >> 5, kk = s & 31;
        const int r = d >> 1;
        const int sl = (((d & 1) * 4 + (kk >> 3)) ^ (r & 7));
        ushort4 v;
        v.x = f2b(acc[i][n][0]); v.y = f2b(acc[i][n][1]);
        v.z = f2b(acc[i][n][2]); v.w = f2b(acc[i][n][3]);
        *reinterpret_cast<ushort4*>(
            &Vc[((size_t)(bh * 64 + c)) * 2048 + r * 64 + sl * 8 + (kk & 7)]) = v;
      } else if (which == 1) {
        #pragma unroll
        for (int j = 0; j < 4; ++j) {
          const int ss = s + j;
          const int c = ss >> 5, r = ss & 31;
          const int dsw = (((d >> 3) ^ (r & 7)) << 3) | (d & 7);
          Kc[(((size_t)(bh * 64 + c)) * 32 + r) * 64 + dsw] = f2b(acc[i][n][j]);
        }
      } else {
        unsigned short* dst = Qb + ((size_t)bh * 2048 + s) * 64 + d;
        #pragma unroll
        for (int j = 0; j < 4; ++j) dst[j * 64] = f2b(acc[i][n][j] * CS);
      }
    }
  }
}

// ---------------- causal flash attention: fused-pair, shared K/V frags ----------------
// Block owns tile pair (P1, 15-P1) of one bh. Chunks staged in PAIRS (8KB/round),
// triple-buffered, counted vmcnt(4), ONE convergent barrier per round.
// K/V fragments loaded ONCE per chunk and shared by both tiles' math (T5 setprio).

static __device__ __forceinline__ f32x16 mfma32(short8 a, short8 b, f32x16 c) {
  return __builtin_amdgcn_mfma_f32_32x32x16_bf16(a, b, c, 0, 0, 0);
}

struct KVf { short8 k0, k1, k2, k3, v0, v1, v2, v3; };

static __device__ __forceinline__ KVf load_frags(
    const unsigned short* __restrict__ Kl, const unsigned short* __restrict__ Vl,
    int q, int hi) {
  KVf f;
  const int qs = q & 7;
  f.k0 = *reinterpret_cast<const short8*>(Kl + q * 64 + (((0 + hi) ^ qs) << 3));
  f.k1 = *reinterpret_cast<const short8*>(Kl + q * 64 + (((2 + hi) ^ qs) << 3));
  f.k2 = *reinterpret_cast<const short8*>(Kl + q * 64 + (((4 + hi) ^ qs) << 3));
  f.k3 = *reinterpret_cast<const short8*>(Kl + q * 64 + (((6 + hi) ^ qs) << 3));
  const int vr = q >> 1, vs = (q & 1) * 4, vw = vr & 7;
  f.v0 = *reinterpret_cast<const short8*>(Vl + vr * 64 + (((vs + hi) ^ vw) << 3));
  f.v1 = *reinterpret_cast<const short8*>(Vl + vr * 64 + (((vs + 2 + hi) ^ vw) << 3));
  f.v2 = *reinterpret_cast<const short8*>(Vl + (vr + 16) * 64 + (((vs + hi) ^ vw) << 3));
  f.v3 = *reinterpret_cast<const short8*>(Vl + (vr + 16) * 64 + (((vs + 2 + hi) ^ vw) << 3));
  return f;
}

template<bool MASKED>
static __device__ __forceinline__ void tile_math(const KVf& f, int q, int hi,
    const short8& Qf0, const short8& Qf1, const short8& Qf2, const short8& Qf3,
    f32x16& accA, f32x16& accB, float& lsum) {
  f32x16 s = {0.f,0.f,0.f,0.f,0.f,0.f,0.f,0.f,0.f,0.f,0.f,0.f,0.f,0.f,0.f,0.f};
  __builtin_amdgcn_s_setprio(1);
  s = mfma32(f.k0, Qf0, s);
  s = mfma32(f.k1, Qf1, s);
  s = mfma32(f.k2, Qf2, s);
  s = mfma32(f.k3, Qf3, s);
  __builtin_amdgcn_s_setprio(0);

  float p[16];
  #pragma unroll
  for (int r = 0; r < 16; ++r) {
    if (MASKED) {
      const int kr = (r & 3) + 8 * (r >> 2) + 4 * hi;
      p[r] = (kr <= q) ? __builtin_amdgcn_exp2f(s[r]) : 0.f;
    } else {
      p[r] = __builtin_amdgcn_exp2f(s[r]);
    }
  }
  float t0 = (p[0] + p[1]) + (p[2] + p[3]);
  float t1 = (p[4] + p[5]) + (p[6] + p[7]);
  float t2 = (p[8] + p[9]) + (p[10] + p[11]);
  float t3 = (p[12] + p[13]) + (p[14] + p[15]);
  lsum += (t0 + t1) + (t2 + t3);

  unsigned W[8], X[8];
  #pragma unroll
  for (int i = 0; i < 8; ++i)
    asm("v_cvt_pk_bf16_f32 %0, %1, %2" : "=v"(W[i]) : "v"(p[2 * i]), "v"(p[2 * i + 1]));
  #pragma unroll
  for (int i = 0; i < 8; ++i) X[i] = __shfl_xor(W[i], 32);

  union { unsigned u[4]; short8 v; } fa0, fa1;
  fa0.u[0] = hi ? X[2] : W[0];
  fa0.u[1] = hi ? X[3] : W[1];
  fa0.u[2] = hi ? W[2] : X[0];
  fa0.u[3] = hi ? W[3] : X[1];
  fa1.u[0] = hi ? X[6] : W[4];
  fa1.u[1] = hi ? X[7] : W[5];
  fa1.u[2] = hi ? W[6] : X[4];
  fa1.u[3] = hi ? W[7] : X[5];

  __builtin_amdgcn_s_setprio(1);
  accA = mfma32(fa0.v, f.v0, accA);
  accA = mfma32(fa1.v, f.v1, accA);
  accB = mfma32(fa0.v, f.v2, accB);
  accB = mfma32(fa1.v, f.v3, accB);
  __builtin_amdgcn_s_setprio(0);
}

// Zb is written slot-swizzled (it feeds k_gemm_out's A-staging).
static __device__ __forceinline__ void store_tile(unsigned short* __restrict__ Zb,
    int b_, int h, int q0, int q, int hi,
    const f32x16& a0, const f32x16& a1, float lsum) {
  const float lt = lsum + __shfl_xor(lsum, 32);
  const float rl = 1.f / lt;
  #pragma unroll
  for (int r = 0; r < 16; ++r) {
    const int qr = (r & 3) + 8 * (r >> 2) + 4 * hi;
    const float rlr = __shfl(rl, qr);
    const int row = b_ * 2048 + q0 + qr;
    const int sl = (((q >> 3) ^ ((qr >> 1) & 3)) << 3) + (q & 7);
    unsigned short* dst = Zb + (size_t)row * 1024 + h * 64;
    dst[sl]      = f2b(a0[r] * rlr);
    dst[32 + sl] = f2b(a1[r] * rlr);
  }
}

__global__ __launch_bounds__(256, 2) void k_attn(const unsigned short* __restrict__ Qb,
                                                 const unsigned short* __restrict__ Kc,
                                                 const unsigned short* __restrict__ Vc,
                                                 unsigned short* __restrict__ Zb) {
  __shared__ __align__(16) unsigned short Kbuf[3][2][2048];
  __shared__ __align__(16) unsigned short Vbuf[3][2][2048];
  const int tid = threadIdx.x;
  const int lane = tid & 63, w = tid >> 6;
  const int q = lane & 31, hi = lane >> 5;
  // decode: XCD-pinned bh; co-resident block pairs get complementary P1 and same bh.
  const int bid = blockIdx.x;                  // 0..511
  const int g = bid & 7;                       // XCD
  const int sdec = bid >> 3;                   // 0..63
  const int par = sdec & 1;
  const int jj = sdec >> 1;                    // 0..31
  const int bh = g * 8 + (jj & 7);
  const int x = jj >> 3;                       // 0..3
  const int P1 = par ? (7 - x) : x;            // 0..7
  const int q0A = 128 * P1 + 32 * w;
  const int q0B = 128 * (15 - P1) + 32 * w;
  const int cmaxA = 4 * P1 + w;
  const int cmaxB = 4 * (15 - P1) + w;
  const int C = 4 * (15 - P1) + 4;             // chunks staged; always even
  const int R = C >> 1;                        // pair rounds
  const int b_ = bh >> 4, h = bh & 15;

  const unsigned short* Qbh = Qb + (size_t)bh * 2048 * 64;
  const unsigned short* Kch = Kc + (size_t)bh * 64 * 2048;
  const unsigned short* Vch = Vc + (size_t)bh * 64 * 2048;

  const unsigned short* QpA = Qbh + (size_t)(q0A + q) * 64 + hi * 8;
  const short8 QA0 = *reinterpret_cast<const short8*>(QpA);
  const short8 QA1 = *reinterpret_cast<const short8*>(QpA + 16);
  const short8 QA2 = *reinterpret_cast<const short8*>(QpA + 32);
  const short8 QA3 = *reinterpret_cast<const short8*>(QpA + 48);
  const unsigned short* QpB = Qbh + (size_t)(q0B + q) * 64 + hi * 8;
  const short8 QB0 = *reinterpret_cast<const short8*>(QpB);
  const short8 QB1 = *reinterpret_cast<const short8*>(QpB + 16);
  const short8 QB2 = *reinterpret_cast<const short8*>(QpB + 32);
  const short8 QB3 = *reinterpret_cast<const short8*>(QpB + 48);

  const f32x16 zero = {0.f,0.f,0.f,0.f,0.f,0.f,0.f,0.f,0.f,0.f,0.f,0.f,0.f,0.f,0.f,0.f};
  f32x16 aA0 = zero, aA1 = zero, aB0 = zero, aB1 = zero;
  float lA = 0.f, lB = 0.f;

#define STAGE_PAIR(r, si)                                                     \
    GLDS16(Kch + (size_t)(2 * (r)) * 2048 + tid * 8,     &Kbuf[si][0][tid * 8]); \
    GLDS16(Vch + (size_t)(2 * (r)) * 2048 + tid * 8,     &Vbuf[si][0][tid * 8]); \
    GLDS16(Kch + (size_t)(2 * (r) + 1) * 2048 + tid * 8, &Kbuf[si][1][tid * 8]); \
    GLDS16(Vch + (size_t)(2 * (r) + 1) * 2048 + tid * 8, &Vbuf[si][1][tid * 8]);

  STAGE_PAIR(0, 0);
  STAGE_PAIR(1, 1);

  int ci = 0, si = 2;
  for (int r = 0; r < R; ++r) {
    if (r == R - 1) { VM0; }
    else            { asm volatile("s_waitcnt vmcnt(4)" ::: "memory"); }
    __syncthreads();                           // pair r visible; prior readers done
    if (r + 2 < R) { STAGE_PAIR(r + 2, si); }
    #pragma unroll
    for (int half = 0; half < 2; ++half) {
      const int c = 2 * r + half;
      if (c <= cmaxB) {
        const KVf f = load_frags(Kbuf[ci][half], Vbuf[ci][half], q, hi);
        if (c <= cmaxA) {
          if (c == cmaxA)
            tile_math<true >(f, q, hi, QA0, QA1, QA2, QA3, aA0, aA1, lA);
          else
            tile_math<false>(f, q, hi, QA0, QA1, QA2, QA3, aA0, aA1, lA);
        }
        if (c == cmaxB)
          tile_math<true >(f, q, hi, QB0, QB1, QB2, QB3, aB0, aB1, lB);
        else
          tile_math<false>(f, q, hi, QB0, QB1, QB2, QB3, aB0, aB1, lB);
      }
    }
    ci = (ci + 1 == 3) ? 0 : ci + 1;
    si = (si + 1 == 3) ? 0 : si + 1;
  }
  store_tile(Zb, b_, h, q0A, q, hi, aA0, aA1, lA);
  store_tile(Zb, b_, h, q0B, q, hi, aB0, aB1, lB);
#undef STAGE_PAIR
}

// ---------------- 128x128 GEMM: out = Z @ Wo (BK=64 two-plane, r14 schedule) ----------------
__global__ __launch_bounds__(256) void k_gemm_out(const unsigned short* __restrict__ A,
                                                  const unsigned short* __restrict__ Bt,
                                                  float* __restrict__ Out) {
  __shared__ unsigned short As[2][128 * 32];
  __shared__ unsigned short Bs[2][128 * 32];
  const int bm = blockIdx.x, bn = blockIdx.y;
  const int tid = threadIdx.x;
  const int lane = tid & 63, wid = tid >> 6;
  const int wr = wid >> 1, wc = wid & 1;
  const int fr = lane & 15, fq = lane >> 4;

  f32x4 acc[4][4];
  #pragma unroll
  for (int i = 0; i < 4; ++i)
    #pragma unroll
    for (int n = 0; n < 4; ++n) acc[i][n] = f32x4{0.f, 0.f, 0.f, 0.f};

  const int arow = tid >> 2, acol = (tid & 3) * 8;
  const int lds0 = tid * 8, lds1 = (tid + 256) * 8;
  const unsigned short* aG0 = A + (bm * 128 + arow) * 1024 + acol;
  const unsigned short* aG1 = A + (bm * 128 + arow + 64) * 1024 + acol;
  const unsigned short* bG0 = Bt + (bn * 128 + arow) * 1024 + acol;
  const unsigned short* bG1 = Bt + (bn * 128 + arow + 64) * 1024 + acol;

  const int rowA = (wr * 64 + fr) * 32;
  const int rowB = (wc * 64 + fr) * 32;
  const int slot = ((fq ^ ((fr >> 1) & 3)) << 3);

  for (int k0 = 0; k0 < 1024; k0 += 64) {
    __syncthreads();
    GLDS16(aG0 + k0,      As[0] + lds0);
    GLDS16(aG1 + k0,      As[0] + lds1);
    GLDS16(aG0 + k0 + 32, As[1] + lds0);
    GLDS16(aG1 + k0 + 32, As[1] + lds1);
    GLDS16(bG0 + k0,      Bs[0] + lds0);
    GLDS16(bG1 + k0,      Bs[0] + lds1);
    GLDS16(bG0 + k0 + 32, Bs[1] + lds0);
    GLDS16(bG1 + k0 + 32, Bs[1] + lds1);
    VM0;
    __syncthreads();
    #pragma unroll
    for (int p = 0; p < 2; ++p) {
      short8 a[4], b[4];
      #pragma unroll
      for (int i = 0; i < 4; ++i)
        a[i] = *reinterpret_cast<const short8*>(As[p] + rowA + i * 512 + slot);
      #pragma unroll
      for (int n = 0; n < 4; ++n)
        b[n] = *reinterpret_cast<const short8*>(Bs[p] + rowB + n * 512 + slot);
      #pragma unroll
      for (int i = 0; i < 4; ++i)
        #pragma unroll
        for (int n = 0; n < 4; ++n)
          acc[i][n] = __builtin_amdgcn_mfma_f32_16x16x32_bf16(a[i], b[n], acc[i][n], 0, 0, 0);
    }
  }

  const int colb = bn * 128 + wc * 64 + fr;
  const int rowb = bm * 128 + wr * 64 + fq * 4;
  #pragma unroll
  for (int n = 0; n < 4; ++n) {
    const int col = colb + n * 16;
    #pragma unroll
    for (int i = 0; i < 4; ++i) {
      const int row = rowb + i * 16;
      #pragma unroll
      for (int j = 0; j < 4; ++j) Out[(size_t)(row + j) * 1024 + col] = acc[i][n][j];
    }
  }
}

extern "C" void kernel_launch(void* const* d_in, const int* in_sizes, int n_in,
                              void* d_out, int out_size, void* d_ws, size_t ws_size,
                              hipStream_t stream) {
  const float* resid = (const float*)d_in[0];
  const float* w_q = (const float*)d_in[1];
  const float* w_k = (const float*)d_in[2];
  const float* w_v = (const float*)d_in[3];
  const float* w_o = (const float*)d_in[4];
  float* out = (float*)d_out;

  char* ws = (char*)d_ws;
  const size_t MB = 1u << 20;
  unsigned short* Xb = (unsigned short*)(ws);            // 16 MiB: resid bf16 swz; reused as Zb
  unsigned short* W3 = (unsigned short*)(ws + 16 * MB);  // 6 MiB : fused qkv B^T swz
  unsigned short* Wo = (unsigned short*)(ws + 22 * MB);  // 2 MiB : WoT swz
  unsigned short* Qb = (unsigned short*)(ws + 24 * MB);  // 16 MiB: Q [bh][s][d] (pre-scaled)
  unsigned short* Kc = (unsigned short*)(ws + 40 * MB);  // 16 MiB: K chunked+swizzled blobs
  unsigned short* Vc = (unsigned short*)(ws + 56 * MB);  // 16 MiB: V chunked+swizzled blobs
  unsigned short* Zb = Xb;                               // alias: Xb dead after k_gemm_qkv

  hipLaunchKernelGGL(k_cast, dim3(8192), dim3(256), 0, stream, resid, Xb, 8192 * 1024 / 4);
  hipLaunchKernelGGL(k_trans_qkv, dim3(768), dim3(256), 0, stream, w_q, w_k, w_v, W3);
  hipLaunchKernelGGL(k_trans_wo, dim3(256), dim3(256), 0, stream, w_o, Wo);
  hipLaunchKernelGGL(k_gemm_qkv, dim3(64, 24), dim3(256), 0, stream, Xb, W3, Qb, Kc, Vc);
  hipLaunchKernelGGL(k_attn, dim3(512), dim3(256), 0, stream, Qb, Kc, Vc, Zb);
  hipLaunchKernelGGL(k_gemm_out, dim3(64, 8), dim3(256), 0, stream, Zb, Wo, out);
}